// Round 2
// baseline (787.113 us; speedup 1.0000x reference)
//
#include <hip/hip_runtime.h>
#include <math.h>

// Shapes (fixed per setup_inputs)
#define S_LEN 1024
#define DMODEL 1024
#define NH 8
#define DH 64
#define DR 32
#define DCKV 256
#define DCQ 512
#define KSEL 128
#define LWIN 64

__device__ __forceinline__ float sp_softplus(float x) {
    // matches jax.nn.softplus = logaddexp(x, 0)
    return fmaxf(x, 0.f) + log1pf(expf(-fabsf(x)));
}

// ---------------- generic fp32 GEMM: C[M,N] = A[M,K] @ B[K,N] ----------------
// BM=32, BN=64, BK=16, 256 threads, 2x4 micro-tile. M must be multiple of 32,
// K multiple of 16; N guarded. grid.z batching via sAz/sBz/sCz (float strides).
#define GBM 32
#define GBN 64
#define GBK 16
__global__ __launch_bounds__(256) void gemm_f32(
    const float* __restrict__ A, const float* __restrict__ B, float* __restrict__ C,
    int M, int N, int K, int lda, int ldb, int ldc,
    long sAz, long sBz, long sCz)
{
    A += (long)blockIdx.z * sAz;
    B += (long)blockIdx.z * sBz;
    C += (long)blockIdx.z * sCz;
    int m0 = blockIdx.y * GBM, n0 = blockIdx.x * GBN;
    __shared__ float As[GBK][GBM + 1];
    __shared__ float Bs[GBK][GBN + 1];
    int tid = threadIdx.x;
    int ty = tid >> 4, tx = tid & 15;
    float acc[2][4] = {};
    for (int k0 = 0; k0 < K; k0 += GBK) {
        {
            int r = tid >> 4, c = tid & 15;
            As[c][r]      = A[(long)(m0 + r) * lda + k0 + c];
            As[c][r + 16] = A[(long)(m0 + r + 16) * lda + k0 + c];
        }
        {
            int kk = tid >> 6, n = tid & 63;
            bool ok = (n0 + n) < N;
            #pragma unroll
            for (int u = 0; u < 4; ++u)
                Bs[kk + u * 4][n] = ok ? B[(long)(k0 + kk + u * 4) * ldb + n0 + n] : 0.f;
        }
        __syncthreads();
        #pragma unroll
        for (int kk = 0; kk < GBK; ++kk) {
            float a0 = As[kk][ty * 2], a1 = As[kk][ty * 2 + 1];
            float b0 = Bs[kk][tx * 4], b1 = Bs[kk][tx * 4 + 1];
            float b2 = Bs[kk][tx * 4 + 2], b3 = Bs[kk][tx * 4 + 3];
            acc[0][0] += a0 * b0; acc[0][1] += a0 * b1; acc[0][2] += a0 * b2; acc[0][3] += a0 * b3;
            acc[1][0] += a1 * b0; acc[1][1] += a1 * b1; acc[1][2] += a1 * b2; acc[1][3] += a1 * b3;
        }
        __syncthreads();
    }
    #pragma unroll
    for (int i = 0; i < 2; ++i) {
        int row = m0 + ty * 2 + i;
        #pragma unroll
        for (int j = 0; j < 4; ++j) {
            int col = n0 + tx * 4 + j;
            if (col < N) C[(long)row * ldc + col] = acc[i][j];
        }
    }
}

// ---------------- PoPE for queries: pre (1024 x 256) -> out (1024 x [h][32]) --
__global__ __launch_bounds__(128) void pope_q_kernel(
    const float* __restrict__ pre, const float* __restrict__ raw_delta,
    float* __restrict__ outq)
{
    int t = blockIdx.x, tid = threadIdx.x;
    int h = tid >> 4, i = tid & 15;
    float rd = raw_delta[i];
    float delta = -6.283185307179586f * (1.f / (1.f + expf(-rd)));
    float th = powf(10000.f, -(float)i * 0.0625f);
    float ang = (float)t * th + delta;
    float sv, cv;
    sincosf(ang, &sv, &cv);
    float m1 = sp_softplus(pre[t * 256 + h * 32 + i]);
    float m2 = sp_softplus(pre[t * 256 + h * 32 + 16 + i]);
    outq[t * 256 + h * 32 + i]      = m1 * cv - m2 * sv;
    outq[t * 256 + h * 32 + 16 + i] = m1 * sv + m2 * cv;
}

// -------- absorbed query: qabs[t][h][c] = sum_d qc[t, h*64+d] * w_uk[c, h*64+d]
__global__ __launch_bounds__(256) void qabs_kernel(
    const float* __restrict__ qc, const float* __restrict__ w_uk,
    float* __restrict__ qabs)
{
    int h = blockIdx.x;           // 0..7
    int t0 = blockIdx.y * 16;     // 64 tiles
    __shared__ float qcs[16][65];
    __shared__ float wks[16][65];
    int tid = threadIdx.x;
    {
        int r = tid >> 6, d = tid & 63;
        #pragma unroll
        for (int u = 0; u < 4; ++u)
            qcs[r + u * 4][d] = qc[(long)(t0 + r + u * 4) * 512 + h * 64 + d];
    }
    int tt = tid >> 4, cc = tid & 15;
    for (int c0 = 0; c0 < 256; c0 += 16) {
        __syncthreads();
        {
            int r = tid >> 6, d = tid & 63;
            #pragma unroll
            for (int u = 0; u < 4; ++u)
                wks[r + u * 4][d] = w_uk[(long)(c0 + r + u * 4) * 512 + h * 64 + d];
        }
        __syncthreads();
        float acc = 0.f, acc2 = 0.f;
        #pragma unroll
        for (int d = 0; d < 64; d += 2) {
            acc  += qcs[tt][d]     * wks[cc][d];
            acc2 += qcs[tt][d + 1] * wks[cc][d + 1];
        }
        qabs[(long)(t0 + tt) * 2048 + h * 256 + c0 + cc] = acc + acc2;
    }
}

// -------- lightning indexer: I[t][s] = sum_h w_idx[h]*relu(qI[t,h,:].kI[s,:]) --
__global__ __launch_bounds__(256) void indexer_kernel(
    const float* __restrict__ qI, const float* __restrict__ kI,
    const float* __restrict__ w_idx, float* __restrict__ I)
{
    int sb = blockIdx.x, tb = blockIdx.y;
    if (sb > tb) return;  // strictly-future tile: never read by top-k
    int t0 = tb * 64, s0 = sb * 64;
    __shared__ float qs[64][65];
    __shared__ float ks[64][65];
    int tid = threadIdx.x;
    int ty = tid >> 4, tx = tid & 15;
    {
        int rr = tid >> 6, d = tid & 63;   // rr*16+u covers all 64 rows
        #pragma unroll
        for (int u = 0; u < 16; ++u)
            ks[rr * 16 + u][d] = kI[(long)(s0 + rr * 16 + u) * 64 + d];
    }
    float accI[4][4] = {};
    for (int h = 0; h < 8; ++h) {
        __syncthreads();
        {
            int rr = tid >> 6, d = tid & 63;
            #pragma unroll
            for (int u = 0; u < 16; ++u)
                qs[rr * 16 + u][d] = qI[(long)(t0 + rr * 16 + u) * 512 + h * 64 + d];
        }
        __syncthreads();
        float acc[4][4] = {};
        #pragma unroll 8
        for (int d = 0; d < 64; ++d) {
            float a[4], b[4];
            #pragma unroll
            for (int i = 0; i < 4; ++i) a[i] = qs[ty * 4 + i][d];
            #pragma unroll
            for (int j = 0; j < 4; ++j) b[j] = ks[tx * 4 + j][d];
            #pragma unroll
            for (int i = 0; i < 4; ++i)
                #pragma unroll
                for (int j = 0; j < 4; ++j) acc[i][j] += a[i] * b[j];
        }
        float wh = w_idx[h];
        #pragma unroll
        for (int i = 0; i < 4; ++i)
            #pragma unroll
            for (int j = 0; j < 4; ++j)
                accI[i][j] += wh * fmaxf(acc[i][j], 0.f);
    }
    #pragma unroll
    for (int i = 0; i < 4; ++i) {
        float4 v = make_float4(accI[i][0], accI[i][1], accI[i][2], accI[i][3]);
        *(float4*)&I[(long)(t0 + ty * 4 + i) * 1024 + s0 + tx * 4] = v;
    }
}

// -------- exact top-k (jax.lax.top_k semantics: value desc, ties index asc) ---
// one wave (64 lanes) per query row t; 4 rows per 256-thread block.
__global__ __launch_bounds__(256) void topk_kernel(
    const float* __restrict__ I, int* __restrict__ idxout)
{
    int t = blockIdx.x * 4 + (threadIdx.x >> 6);
    int lane = threadIdx.x & 63;
    int smin = max(0, t - 63);
    int w = min(64, t + 1);                // +inf local-window entries
    if (lane < w) idxout[t * 128 + lane] = smin + lane;
    for (int q = t + 1 + lane; q < 128; q += 64)   // -inf future fill (t<127)
        idxout[t * 128 + q] = q;
    int f = max(0, t - 63);                // finite candidates: s in [0, t-64]
    int m = min(f, 64);
    if (m == 0) return;
    const float* row = I + (long)t * 1024;
    unsigned long long key[16];
    #pragma unroll
    for (int i = 0; i < 16; ++i) {
        int s = i * 64 + lane;
        key[i] = 0ull;
        if (s < f) {
            unsigned u = __float_as_uint(row[s]);
            unsigned ou = (u & 0x80000000u) ? ~u : (u | 0x80000000u); // ordered
            key[i] = ((unsigned long long)ou << 32) | (0xFFFFFFFFu - (unsigned)s);
        }
    }
    for (int it = 0; it < m; ++it) {
        unsigned long long best = key[0];
        #pragma unroll
        for (int i = 1; i < 16; ++i) best = key[i] > best ? key[i] : best;
        #pragma unroll
        for (int off = 32; off > 0; off >>= 1) {
            unsigned long long o = __shfl_xor(best, off, 64);
            best = o > best ? o : best;
        }
        int s = (int)(0xFFFFFFFFu - (unsigned)(best & 0xFFFFFFFFull));
        if (lane == 0) idxout[t * 128 + w + it] = s;
        if ((s & 63) == lane) {
            int slot = s >> 6;
            #pragma unroll
            for (int i = 0; i < 16; ++i)
                if (i == slot) key[i] = 0ull;
        }
    }
}

// -------- fused attention over selected tokens (absorbed form) ----------------
// block per query t, 512 threads. Produces olat[t][h][256].
// Static LDS: 94 KiB (gfx950 allows up to 160 KiB/workgroup; dynamic-shared
// >64 KiB is the risky path, static is the proven one).
__global__ __launch_bounds__(512) void attn_kernel(
    const float* __restrict__ qabs, const float* __restrict__ qrr,
    const float* __restrict__ ckv, const float* __restrict__ xkr,
    const float* __restrict__ raw_delta, const int* __restrict__ idxb,
    float* __restrict__ olat)
{
    __shared__ float ckv_s[64 * 256];
    __shared__ float kr_s[128 * 33];
    __shared__ float qabs_s[8 * 256];
    __shared__ float qr_s[8 * 32];
    __shared__ float sc_s[8 * 128];
    __shared__ int   idx_s[128];

    int t = blockIdx.x, tid = threadIdx.x;

    if (tid < 128) idx_s[tid] = idxb[t * 128 + tid];
    ((float4*)qabs_s)[tid] = ((const float4*)(qabs + (long)t * 2048))[tid];
    if (tid < 64) ((float4*)qr_s)[tid] = ((const float4*)(qrr + (long)t * 256))[tid];
    __syncthreads();

    // kr: PoPE of gathered x@w_kr with position = slot j
    {
        int j = tid >> 2, p = tid & 3;
        int src = idx_s[j];
        #pragma unroll
        for (int u = 0; u < 4; ++u) {
            int i = p * 4 + u;
            float x1 = xkr[src * 32 + i];
            float x2 = xkr[src * 32 + 16 + i];
            float m1 = sp_softplus(x1), m2 = sp_softplus(x2);
            float rd = raw_delta[i];
            float delta = -6.283185307179586f * (1.f / (1.f + expf(-rd)));
            float th = powf(10000.f, -(float)i * 0.0625f);
            float ang = (float)j * th + delta;
            float sv, cv;
            sincosf(ang, &sv, &cv);
            kr_s[j * 33 + i]      = m1 * cv - m2 * sv;
            kr_s[j * 33 + 16 + i] = m1 * sv + m2 * cv;
        }
    }

    const float scale = 0.10206207261596575f; // (64+32)^-0.5
    int h = tid >> 6, jj = tid & 63;
    for (int half = 0; half < 2; ++half) {
        __syncthreads();
        {   // stage 64 gathered ckv rows
            int r = tid >> 3, q = tid & 7;
            int src = idx_s[half * 64 + r];
            const float4* sp4 = (const float4*)(ckv + (long)src * 256);
            float4* dp4 = (float4*)(ckv_s + r * 256);
            #pragma unroll
            for (int u = 0; u < 8; ++u) dp4[q + u * 8] = sp4[q + u * 8];
        }
        __syncthreads();
        {
            const float* qa = qabs_s + h * 256;
            const float* cv = ckv_s + jj * 256;
            float a0 = 0, a1 = 0, a2 = 0, a3 = 0;
            #pragma unroll 8
            for (int cc = 0; cc < 256; cc += 4) {   // rotated reads: no bank conflicts
                int c0 = (cc + jj) & 255;
                int c1 = (cc + 1 + jj) & 255;
                int c2 = (cc + 2 + jj) & 255;
                int c3 = (cc + 3 + jj) & 255;
                a0 += qa[c0] * cv[c0]; a1 += qa[c1] * cv[c1];
                a2 += qa[c2] * cv[c2]; a3 += qa[c3] * cv[c3];
            }
            int j = half * 64 + jj;
            const float* krp = kr_s + j * 33;
            const float* qrp = qr_s + h * 32;
            #pragma unroll 8
            for (int dd = 0; dd < 32; ++dd) {
                int d = (dd + jj) & 31;
                a0 += qrp[d] * krp[d];
            }
            sc_s[h * 128 + j] = scale * (a0 + a1 + a2 + a3);
        }
    }
    __syncthreads();
    {   // softmax per head over 128 (one wave per head)
        float v0 = sc_s[h * 128 + jj], v1 = sc_s[h * 128 + 64 + jj];
        float mx = fmaxf(v0, v1);
        #pragma unroll
        for (int off = 32; off > 0; off >>= 1) mx = fmaxf(mx, __shfl_xor(mx, off, 64));
        float e0 = expf(v0 - mx), e1 = expf(v1 - mx);
        float sm = e0 + e1;
        #pragma unroll
        for (int off = 32; off > 0; off >>= 1) sm += __shfl_xor(sm, off, 64);
        float inv = 1.f / sm;
        sc_s[h * 128 + jj]      = e0 * inv;
        sc_s[h * 128 + 64 + jj] = e1 * inv;
    }
    // o_lat[t][h][c] = sum_j attn[h][j] * ckv_sel[j][c]
    int c = tid & 255, hh = tid >> 8;
    float acc0 = 0, acc1 = 0, acc2 = 0, acc3 = 0;
    for (int half = 0; half < 2; ++half) {
        __syncthreads();
        {
            int r = tid >> 3, q = tid & 7;
            int src = idx_s[half * 64 + r];
            const float4* sp4 = (const float4*)(ckv + (long)src * 256);
            float4* dp4 = (float4*)(ckv_s + r * 256);
            #pragma unroll
            for (int u = 0; u < 8; ++u) dp4[q + u * 8] = sp4[q + u * 8];
        }
        __syncthreads();
        const float* p0 = sc_s + (hh * 4 + 0) * 128 + half * 64;
        const float* p1 = sc_s + (hh * 4 + 1) * 128 + half * 64;
        const float* p2 = sc_s + (hh * 4 + 2) * 128 + half * 64;
        const float* p3 = sc_s + (hh * 4 + 3) * 128 + half * 64;
        #pragma unroll 8
        for (int j2 = 0; j2 < 64; ++j2) {
            float v = ckv_s[j2 * 256 + c];
            acc0 += p0[j2] * v; acc1 += p1[j2] * v;
            acc2 += p2[j2] * v; acc3 += p3[j2] * v;
        }
    }
    float* op = olat + (long)t * 2048 + (hh * 4) * 256 + c;
    op[0] = acc0; op[256] = acc1; op[512] = acc2; op[768] = acc3;
}

extern "C" void kernel_launch(void* const* d_in, const int* in_sizes, int n_in,
                              void* d_out, int out_size, void* d_ws, size_t ws_size,
                              hipStream_t stream)
{
    const float* x         = (const float*)d_in[0];
    const float* w_q_idx   = (const float*)d_in[1];
    const float* w_k_idx   = (const float*)d_in[2];
    const float* w_idx     = (const float*)d_in[3];
    const float* raw_delta = (const float*)d_in[4];
    const float* w_dkv     = (const float*)d_in[5];
    const float* w_uk      = (const float*)d_in[6];
    const float* w_uv      = (const float*)d_in[7];
    const float* w_dq      = (const float*)d_in[8];
    const float* w_uq      = (const float*)d_in[9];
    const float* w_qr      = (const float*)d_in[10];
    const float* w_kr      = (const float*)d_in[11];
    const float* w_out     = (const float*)d_in[12];
    (void)in_sizes; (void)n_in; (void)out_size; (void)ws_size;
    float* out = (float*)d_out;

    float* ws = (float*)d_ws;
    float* qI   = ws;        ws += 1024 * 512;
    float* kI   = ws;        ws += 1024 * 64;
    float* ckv  = ws;        ws += 1024 * 256;
    float* cq   = ws;        ws += 1024 * 512;
    float* xkr  = ws;        ws += 1024 * 32;
    float* qrp  = ws;        ws += 1024 * 256;
    float* qrr  = ws;        ws += 1024 * 256;
    float* qc   = ws;        ws += 1024 * 512;
    float* qabs = ws;        ws += 1024 * 2048;
    float* Ibuf = ws;        ws += 1024 * 1024;
    int*   idxb = (int*)ws;  ws += 1024 * 128;
    float* olat = ws;        ws += 1024 * 2048;
    float* outh = ws;        ws += 1024 * 512;

    dim3 blk(256);
    // x projections
    gemm_f32<<<dim3(8, 32, 1), blk, 0, stream>>>(x, w_q_idx, qI, 1024, 512, 1024, 1024, 512, 512, 0, 0, 0);
    gemm_f32<<<dim3(1, 32, 1), blk, 0, stream>>>(x, w_k_idx, kI, 1024, 64, 1024, 1024, 64, 64, 0, 0, 0);
    gemm_f32<<<dim3(4, 32, 1), blk, 0, stream>>>(x, w_dkv, ckv, 1024, 256, 1024, 1024, 256, 256, 0, 0, 0);
    gemm_f32<<<dim3(8, 32, 1), blk, 0, stream>>>(x, w_dq, cq, 1024, 512, 1024, 1024, 512, 512, 0, 0, 0);
    gemm_f32<<<dim3(1, 32, 1), blk, 0, stream>>>(x, w_kr, xkr, 1024, 32, 1024, 1024, 32, 32, 0, 0, 0);
    // c_q projections
    gemm_f32<<<dim3(8, 32, 1), blk, 0, stream>>>(cq, w_uq, qc, 1024, 512, 512, 512, 512, 512, 0, 0, 0);
    gemm_f32<<<dim3(4, 32, 1), blk, 0, stream>>>(cq, w_qr, qrp, 1024, 256, 512, 512, 256, 256, 0, 0, 0);
    pope_q_kernel<<<dim3(1024), dim3(128), 0, stream>>>(qrp, raw_delta, qrr);
    qabs_kernel<<<dim3(8, 64), blk, 0, stream>>>(qc, w_uk, qabs);
    // indexer + exact top-k
    indexer_kernel<<<dim3(16, 16), blk, 0, stream>>>(qI, kI, w_idx, Ibuf);
    topk_kernel<<<dim3(256), blk, 0, stream>>>(Ibuf, idxb);
    // fused attention -> latent output
    attn_kernel<<<dim3(1024), dim3(512), 0, stream>>>(qabs, qrr, ckv, xkr, raw_delta, idxb, olat);
    // o_lat @ w_uv (per-head, batched over grid.z), then @ w_out
    gemm_f32<<<dim3(1, 32, 8), blk, 0, stream>>>(olat, w_uv, outh, 1024, 64, 256, 2048, 512, 512, 256, 64, 64);
    gemm_f32<<<dim3(16, 32, 1), blk, 0, stream>>>(outh, w_out, out, 1024, 1024, 512, 512, 1024, 1024, 0, 0, 0);
}

// Round 3
// 465.617 us; speedup vs baseline: 1.6905x; 1.6905x over previous
//
#include <hip/hip_runtime.h>
#include <math.h>

// Shapes (fixed per setup_inputs)
#define S_LEN 1024
#define DMODEL 1024
#define NH 8
#define DH 64
#define DR 32
#define DCKV 256
#define DCQ 512
#define KSEL 128
#define LWIN 64

__device__ __forceinline__ float sp_softplus(float x) {
    return fmaxf(x, 0.f) + log1pf(expf(-fabsf(x)));
}

// ---------------- fp32 GEMM v2: C[M,N] = A[M,K] @ B[K,N] ----------------
// 64x64 tile, 256 threads, 4x4 microtile, float4 LDS reads, reg prefetch.
// M % 64 == 0, K % 16 == 0, N % 4 == 0 (N guarded). z-batch via strides.
__global__ __launch_bounds__(256) void gemm64(
    const float* __restrict__ A, const float* __restrict__ B, float* __restrict__ C,
    int N, int K, int lda, int ldb, int ldc,
    long sAz, long sBz, long sCz)
{
    A += (long)blockIdx.z * sAz;
    B += (long)blockIdx.z * sBz;
    C += (long)blockIdx.z * sCz;
    int m0 = blockIdx.y * 64, n0 = blockIdx.x * 64;
    __shared__ float As[16][68];
    __shared__ float Bs[16][68];
    int tid = threadIdx.x;
    int ar = tid >> 2, aq = tid & 3;    // A: row ar (0..63), k-quad aq
    int br = tid >> 4, bc = tid & 15;   // B: k-row br (0..15), n-quad bc
    int ty = tid >> 4, tx = tid & 15;   // compute 4x4
    bool bok = (n0 + bc * 4) < N;

    float4 aN = *(const float4*)(A + (long)(m0 + ar) * lda + aq * 4);
    float4 bN = bok ? *(const float4*)(B + (long)br * ldb + n0 + bc * 4)
                    : make_float4(0.f, 0.f, 0.f, 0.f);
    float acc[4][4] = {};
    for (int k0 = 0; k0 < K; k0 += 16) {
        As[aq * 4 + 0][ar] = aN.x;
        As[aq * 4 + 1][ar] = aN.y;
        As[aq * 4 + 2][ar] = aN.z;
        As[aq * 4 + 3][ar] = aN.w;
        *(float4*)&Bs[br][bc * 4] = bN;
        __syncthreads();
        if (k0 + 16 < K) {
            aN = *(const float4*)(A + (long)(m0 + ar) * lda + (k0 + 16) + aq * 4);
            bN = bok ? *(const float4*)(B + (long)(k0 + 16 + br) * ldb + n0 + bc * 4)
                     : make_float4(0.f, 0.f, 0.f, 0.f);
        }
        #pragma unroll
        for (int kk = 0; kk < 16; ++kk) {
            float4 a = *(float4*)&As[kk][ty * 4];
            float4 b = *(float4*)&Bs[kk][tx * 4];
            acc[0][0] += a.x * b.x; acc[0][1] += a.x * b.y; acc[0][2] += a.x * b.z; acc[0][3] += a.x * b.w;
            acc[1][0] += a.y * b.x; acc[1][1] += a.y * b.y; acc[1][2] += a.y * b.z; acc[1][3] += a.y * b.w;
            acc[2][0] += a.z * b.x; acc[2][1] += a.z * b.y; acc[2][2] += a.z * b.z; acc[2][3] += a.z * b.w;
            acc[3][0] += a.w * b.x; acc[3][1] += a.w * b.y; acc[3][2] += a.w * b.z; acc[3][3] += a.w * b.w;
        }
        __syncthreads();
    }
    #pragma unroll
    for (int i = 0; i < 4; ++i) {
        long row = (long)(m0 + ty * 4 + i) * ldc;
        #pragma unroll
        for (int j = 0; j < 4; ++j) {
            int col = n0 + tx * 4 + j;
            if (col < N) C[row + col] = acc[i][j];
        }
    }
}

// ---------------- PoPE for queries: pre (1024 x 256) -> out (1024 x [h][32]) --
__global__ __launch_bounds__(128) void pope_q_kernel(
    const float* __restrict__ pre, const float* __restrict__ raw_delta,
    float* __restrict__ outq)
{
    int t = blockIdx.x, tid = threadIdx.x;
    int h = tid >> 4, i = tid & 15;
    float rd = raw_delta[i];
    float delta = -6.283185307179586f * (1.f / (1.f + expf(-rd)));
    float th = exp2f(-(float)i * 0.83048202372184f);   // 10000^(-i/16)
    float ang = (float)t * th + delta;
    float sv, cv;
    sincosf(ang, &sv, &cv);
    float m1 = sp_softplus(pre[t * 256 + h * 32 + i]);
    float m2 = sp_softplus(pre[t * 256 + h * 32 + 16 + i]);
    outq[t * 256 + h * 32 + i]      = m1 * cv - m2 * sv;
    outq[t * 256 + h * 32 + 16 + i] = m1 * sv + m2 * cv;
}

// -------- mu = softplus(x @ w_kr), elementwise over 1024x32 -------------------
__global__ __launch_bounds__(256) void mu_kernel(
    const float* __restrict__ xkr, float* __restrict__ mu)
{
    int i = blockIdx.x * 256 + threadIdx.x;
    mu[i] = sp_softplus(xkr[i]);
}

// -------- cos/sin table for key PoPE: pos j=0..127, i=0..15 -------------------
__global__ __launch_bounds__(256) void cs_kernel(
    const float* __restrict__ raw_delta, float* __restrict__ csc, float* __restrict__ css)
{
    int idx = blockIdx.x * 256 + threadIdx.x;   // 2048 entries
    int j = idx >> 4, i = idx & 15;
    float rd = raw_delta[i];
    float delta = -6.283185307179586f * (1.f / (1.f + expf(-rd)));
    float th = exp2f(-(float)i * 0.83048202372184f);
    float ang = (float)j * th + delta;
    float sv, cv;
    sincosf(ang, &sv, &cv);
    csc[idx] = cv;
    css[idx] = sv;
}

// -------- absorbed query: qabs[t][h][c] = sum_d qc[t, h*64+d] * w_uk[c, h*64+d]
__global__ __launch_bounds__(256) void qabs_kernel(
    const float* __restrict__ qc, const float* __restrict__ w_uk,
    float* __restrict__ qabs)
{
    int h = blockIdx.x;
    int t0 = blockIdx.y * 16;
    __shared__ float qcs[16][65];
    __shared__ float wks[16][65];
    int tid = threadIdx.x;
    {
        int r = tid >> 6, d = tid & 63;
        #pragma unroll
        for (int u = 0; u < 4; ++u)
            qcs[r + u * 4][d] = qc[(long)(t0 + r + u * 4) * 512 + h * 64 + d];
    }
    int tt = tid >> 4, cc = tid & 15;
    for (int c0 = 0; c0 < 256; c0 += 16) {
        __syncthreads();
        {
            int r = tid >> 6, d = tid & 63;
            #pragma unroll
            for (int u = 0; u < 4; ++u)
                wks[r + u * 4][d] = w_uk[(long)(c0 + r + u * 4) * 512 + h * 64 + d];
        }
        __syncthreads();
        float acc = 0.f, acc2 = 0.f;
        #pragma unroll
        for (int d = 0; d < 64; d += 2) {
            acc  += qcs[tt][d]     * wks[cc][d];
            acc2 += qcs[tt][d + 1] * wks[cc][d + 1];
        }
        qabs[(long)(t0 + tt) * 2048 + h * 256 + c0 + cc] = acc + acc2;
    }
}

// -------- lightning indexer: I[t][s] = sum_h w_idx[h]*relu(qI[t,h,:].kI[s,:]) --
__global__ __launch_bounds__(256) void indexer_kernel(
    const float* __restrict__ qI, const float* __restrict__ kI,
    const float* __restrict__ w_idx, float* __restrict__ I)
{
    int sb = blockIdx.x, tb = blockIdx.y;
    if (sb > tb) return;
    int t0 = tb * 64, s0 = sb * 64;
    __shared__ float qs[64][65];
    __shared__ float ks[64][65];
    int tid = threadIdx.x;
    int ty = tid >> 4, tx = tid & 15;
    {
        int rr = tid >> 6, d = tid & 63;
        #pragma unroll
        for (int u = 0; u < 16; ++u)
            ks[rr * 16 + u][d] = kI[(long)(s0 + rr * 16 + u) * 64 + d];
    }
    float accI[4][4] = {};
    for (int h = 0; h < 8; ++h) {
        __syncthreads();
        {
            int rr = tid >> 6, d = tid & 63;
            #pragma unroll
            for (int u = 0; u < 16; ++u)
                qs[rr * 16 + u][d] = qI[(long)(t0 + rr * 16 + u) * 512 + h * 64 + d];
        }
        __syncthreads();
        float acc[4][4] = {};
        #pragma unroll 8
        for (int d = 0; d < 64; ++d) {
            float a[4], b[4];
            #pragma unroll
            for (int i = 0; i < 4; ++i) a[i] = qs[ty * 4 + i][d];
            #pragma unroll
            for (int j = 0; j < 4; ++j) b[j] = ks[tx * 4 + j][d];
            #pragma unroll
            for (int i = 0; i < 4; ++i)
                #pragma unroll
                for (int j = 0; j < 4; ++j) acc[i][j] += a[i] * b[j];
        }
        float wh = w_idx[h];
        #pragma unroll
        for (int i = 0; i < 4; ++i)
            #pragma unroll
            for (int j = 0; j < 4; ++j)
                accI[i][j] += wh * fmaxf(acc[i][j], 0.f);
    }
    #pragma unroll
    for (int i = 0; i < 4; ++i) {
        float4 v = make_float4(accI[i][0], accI[i][1], accI[i][2], accI[i][3]);
        *(float4*)&I[(long)(t0 + ty * 4 + i) * 1024 + s0 + tx * 4] = v;
    }
}

// -------- exact top-k (jax.lax.top_k semantics: value desc, ties index asc) ---
__global__ __launch_bounds__(256) void topk_kernel(
    const float* __restrict__ I, int* __restrict__ idxout)
{
    int t = blockIdx.x * 4 + (threadIdx.x >> 6);
    int lane = threadIdx.x & 63;
    int smin = max(0, t - 63);
    int w = min(64, t + 1);
    if (lane < w) idxout[t * 128 + lane] = smin + lane;
    for (int q = t + 1 + lane; q < 128; q += 64)
        idxout[t * 128 + q] = q;
    int f = max(0, t - 63);
    int m = min(f, 64);
    if (m == 0) return;
    const float* row = I + (long)t * 1024;
    unsigned long long key[16];
    #pragma unroll
    for (int i = 0; i < 16; ++i) {
        int s = i * 64 + lane;
        key[i] = 0ull;
        if (s < f) {
            unsigned u = __float_as_uint(row[s]);
            unsigned ou = (u & 0x80000000u) ? ~u : (u | 0x80000000u);
            key[i] = ((unsigned long long)ou << 32) | (0xFFFFFFFFu - (unsigned)s);
        }
    }
    for (int it = 0; it < m; ++it) {
        unsigned long long best = key[0];
        #pragma unroll
        for (int i = 1; i < 16; ++i) best = key[i] > best ? key[i] : best;
        #pragma unroll
        for (int off = 32; off > 0; off >>= 1) {
            unsigned long long o = __shfl_xor(best, off, 64);
            best = o > best ? o : best;
        }
        int s = (int)(0xFFFFFFFFu - (unsigned)(best & 0xFFFFFFFFull));
        if (lane == 0) idxout[t * 128 + w + it] = s;
        if ((s & 63) == lane) {
            int slot = s >> 6;
            #pragma unroll
            for (int i = 0; i < 16; ++i)
                if (i == slot) key[i] = 0ull;
        }
    }
}

// -------- fused attention v2: flash-style over 4 chunks of 32 slots -----------
// block per query t, 512 threads (wave w = head h). LDS ~51 KB -> 3 blocks/CU.
__global__ __launch_bounds__(512) void attn_kernel(
    const float* __restrict__ qabs, const float* __restrict__ qrr,
    const float* __restrict__ ckv, const float* __restrict__ mu,
    const float* __restrict__ csc, const float* __restrict__ css,
    const int* __restrict__ idxb, float* __restrict__ olat)
{
    __shared__ float ckvT[256 * 33];   // [c][j-local], pad 33: conflict-free cols
    __shared__ float krT[32 * 33];     // [i][j-local]
    __shared__ float qa_s[8 * 256];    // pre-scaled absorbed q
    __shared__ float qr_s[8 * 32];     // pre-scaled rope q
    __shared__ int   idx_s[128];

    int t = blockIdx.x, tid = threadIdx.x;
    int h = tid >> 6, l = tid & 63;
    const float scale = 0.10206207261596575f;   // (64+32)^-0.5

    if (tid < 128) idx_s[tid] = idxb[t * 128 + tid];
    {
        float4 v = ((const float4*)(qabs + (long)t * 2048))[tid];
        v.x *= scale; v.y *= scale; v.z *= scale; v.w *= scale;
        ((float4*)qa_s)[tid] = v;
    }
    if (tid < 64) {
        float4 v = ((const float4*)(qrr + (long)t * 256))[tid];
        v.x *= scale; v.y *= scale; v.z *= scale; v.w *= scale;
        ((float4*)qr_s)[tid] = v;
    }
    __syncthreads();

    float m_run = -INFINITY, l_run = 0.f;
    float acc0 = 0.f, acc1 = 0.f, acc2 = 0.f, acc3 = 0.f;
    int jq = l & 31, ch = l >> 5;   // QK: local slot jq, c-half ch

    for (int chunk = 0; chunk < 4; ++chunk) {
        int j0 = chunk * 32;
        {   // stage ckvT (transposed): 32 gathered rows x 256 c
            int jl = tid & 31, cq = tid >> 5;      // cq 0..15
            int src = idx_s[j0 + jl];
            const float4* sp4 = (const float4*)(ckv + (long)src * 256);
            #pragma unroll
            for (int g = 0; g < 4; ++g) {
                float4 v = sp4[cq * 4 + g];
                int c = cq * 16 + g * 4;
                ckvT[(c + 0) * 33 + jl] = v.x;
                ckvT[(c + 1) * 33 + jl] = v.y;
                ckvT[(c + 2) * 33 + jl] = v.z;
                ckvT[(c + 3) * 33 + jl] = v.w;
            }
        }
        {   // stage krT: kr[j][i] = PoPE(mu[src], pos=j) transposed
            int jl = tid >> 4, i = tid & 15;       // jl 0..31
            int src = idx_s[j0 + jl];
            float m1 = mu[src * 32 + i];
            float m2 = mu[src * 32 + 16 + i];
            float cv = csc[(j0 + jl) * 16 + i];
            float sv = css[(j0 + jl) * 16 + i];
            krT[i * 33 + jl]        = m1 * cv - m2 * sv;
            krT[(i + 16) * 33 + jl] = m1 * sv + m2 * cv;
        }
        __syncthreads();

        // QK: S[h][j0+jq] ; lane (jq, ch) sums its c-half
        float S = 0.f;
        {
            const float* qa = qa_s + h * 256 + ch * 128;
            const float* cvb = ckvT + (ch * 128) * 33 + jq;
            #pragma unroll 8
            for (int c4 = 0; c4 < 32; ++c4) {
                float4 q4 = *(const float4*)(qa + c4 * 4);
                S += q4.x * cvb[(c4 * 4 + 0) * 33];
                S += q4.y * cvb[(c4 * 4 + 1) * 33];
                S += q4.z * cvb[(c4 * 4 + 2) * 33];
                S += q4.w * cvb[(c4 * 4 + 3) * 33];
            }
            const float* qr = qr_s + h * 32 + ch * 16;
            const float* krb = krT + (ch * 16) * 33 + jq;
            #pragma unroll
            for (int i4 = 0; i4 < 4; ++i4) {
                float4 r4 = *(const float4*)(qr + i4 * 4);
                S += r4.x * krb[(i4 * 4 + 0) * 33];
                S += r4.y * krb[(i4 * 4 + 1) * 33];
                S += r4.z * krb[(i4 * 4 + 2) * 33];
                S += r4.w * krb[(i4 * 4 + 3) * 33];
            }
        }
        S += __shfl_xor(S, 32);   // combine c-halves; both halves now identical

        // online softmax (per wave = per head; all lanes uniform)
        float mx = S;
        #pragma unroll
        for (int off = 16; off > 0; off >>= 1) mx = fmaxf(mx, __shfl_xor(mx, off));
        float m_new = fmaxf(m_run, mx);
        float r = expf(m_run - m_new);
        float p = expf(S - m_new);
        float ps = p;
        #pragma unroll
        for (int off = 16; off > 0; off >>= 1) ps += __shfl_xor(ps, off);
        l_run = l_run * r + ps;
        m_run = m_new;
        acc0 *= r; acc1 *= r; acc2 *= r; acc3 *= r;

        // PV: lane owns c = u*64 + l (u=0..3); p broadcast via shuffle
        {
            const float* cvb = ckvT + l * 33;
            #pragma unroll 8
            for (int j = 0; j < 32; ++j) {
                float pj = __shfl(p, j);
                acc0 += pj * cvb[(0 * 64) * 33 + j];
                acc1 += pj * cvb[(1 * 64) * 33 + j];
                acc2 += pj * cvb[(2 * 64) * 33 + j];
                acc3 += pj * cvb[(3 * 64) * 33 + j];
            }
        }
        __syncthreads();
    }

    float inv = 1.f / l_run;
    float* op = olat + (long)t * 2048 + h * 256 + l;
    op[0]   = acc0 * inv;
    op[64]  = acc1 * inv;
    op[128] = acc2 * inv;
    op[192] = acc3 * inv;
}

extern "C" void kernel_launch(void* const* d_in, const int* in_sizes, int n_in,
                              void* d_out, int out_size, void* d_ws, size_t ws_size,
                              hipStream_t stream)
{
    const float* x         = (const float*)d_in[0];
    const float* w_q_idx   = (const float*)d_in[1];
    const float* w_k_idx   = (const float*)d_in[2];
    const float* w_idx     = (const float*)d_in[3];
    const float* raw_delta = (const float*)d_in[4];
    const float* w_dkv     = (const float*)d_in[5];
    const float* w_uk      = (const float*)d_in[6];
    const float* w_uv      = (const float*)d_in[7];
    const float* w_dq      = (const float*)d_in[8];
    const float* w_uq      = (const float*)d_in[9];
    const float* w_qr      = (const float*)d_in[10];
    const float* w_kr      = (const float*)d_in[11];
    const float* w_out     = (const float*)d_in[12];
    (void)in_sizes; (void)n_in; (void)out_size; (void)ws_size;
    float* out = (float*)d_out;

    float* ws = (float*)d_ws;
    float* qI   = ws;        ws += 1024 * 512;
    float* kI   = ws;        ws += 1024 * 64;
    float* ckv  = ws;        ws += 1024 * 256;
    float* cq   = ws;        ws += 1024 * 512;
    float* xkr  = ws;        ws += 1024 * 32;
    float* qrp  = ws;        ws += 1024 * 256;
    float* qrr  = ws;        ws += 1024 * 256;
    float* qc   = ws;        ws += 1024 * 512;
    float* qabs = ws;        ws += 1024 * 2048;
    float* Ibuf = ws;        ws += 1024 * 1024;
    int*   idxb = (int*)ws;  ws += 1024 * 128;
    float* olat = ws;        ws += 1024 * 2048;
    float* outh = ws;        ws += 1024 * 512;
    float* mu   = ws;        ws += 1024 * 32;
    float* cscb = ws;        ws += 128 * 16;
    float* cssb = ws;        ws += 128 * 16;

    dim3 blk(256);
    // x projections
    gemm64<<<dim3(8, 16), blk, 0, stream>>>(x, w_q_idx, qI, 512, 1024, 1024, 512, 512, 0, 0, 0);
    gemm64<<<dim3(1, 16), blk, 0, stream>>>(x, w_k_idx, kI, 64, 1024, 1024, 64, 64, 0, 0, 0);
    gemm64<<<dim3(4, 16), blk, 0, stream>>>(x, w_dkv, ckv, 256, 1024, 1024, 256, 256, 0, 0, 0);
    gemm64<<<dim3(8, 16), blk, 0, stream>>>(x, w_dq, cq, 512, 1024, 1024, 512, 512, 0, 0, 0);
    gemm64<<<dim3(1, 16), blk, 0, stream>>>(x, w_kr, xkr, 32, 1024, 1024, 32, 32, 0, 0, 0);
    // c_q projections
    gemm64<<<dim3(8, 16), blk, 0, stream>>>(cq, w_uq, qc, 512, 512, 512, 512, 512, 0, 0, 0);
    gemm64<<<dim3(4, 16), blk, 0, stream>>>(cq, w_qr, qrp, 256, 512, 512, 256, 256, 0, 0, 0);
    pope_q_kernel<<<dim3(1024), dim3(128), 0, stream>>>(qrp, raw_delta, qrr);
    qabs_kernel<<<dim3(8, 64), blk, 0, stream>>>(qc, w_uk, qabs);
    mu_kernel<<<dim3(128), blk, 0, stream>>>(xkr, mu);
    cs_kernel<<<dim3(8), blk, 0, stream>>>(raw_delta, cscb, cssb);
    // indexer + exact top-k
    indexer_kernel<<<dim3(16, 16), blk, 0, stream>>>(qI, kI, w_idx, Ibuf);
    topk_kernel<<<dim3(256), blk, 0, stream>>>(Ibuf, idxb);
    // fused attention -> latent output
    attn_kernel<<<dim3(1024), dim3(512), 0, stream>>>(qabs, qrr, ckv, mu, cscb, cssb, idxb, olat);
    // o_lat @ w_uv (per-head, batched over grid.z), then @ w_out
    gemm64<<<dim3(1, 16, 8), blk, 0, stream>>>(olat, w_uv, outh, 64, 256, 2048, 512, 512, 256, 64, 64);
    gemm64<<<dim3(16, 16), blk, 0, stream>>>(outh, w_out, out, 1024, 512, 512, 1024, 1024, 0, 0, 0);
}

// Round 4
// 308.688 us; speedup vs baseline: 2.5499x; 1.5084x over previous
//
#include <hip/hip_runtime.h>
#include <math.h>

// Shapes (fixed per setup_inputs)
#define S_LEN 1024
#define DMODEL 1024
#define NH 8
#define DH 64
#define DR 32
#define DCKV 256
#define DCQ 512
#define KSEL 128
#define LWIN 64

__device__ __forceinline__ float sp_softplus(float x) {
    return fmaxf(x, 0.f) + log1pf(expf(-fabsf(x)));
}

// ---------------- routed multi-GEMM: up to 8 sub-GEMMs in one launch ---------
// Each entry e: C_e[M,N_e] = A_e[M,K_e] @ B_e[K_e,N_e]. BM=32, BN=64, BK=16,
// 128 threads, 4x4 microtile. M=1024 (32 row-tiles, blockIdx.y), col-tiles
// routed by blockIdx.x via tstart. K%16==0, N%4==0 (N guarded vs 64-tile).
// NOTE: per-output accumulation is k-ascending fp32 — bitwise identical to the
// previous gemm64, keeping the top-k selection path stable (absmax canary).
struct MG8 {
    const float* A[8]; const float* B[8]; float* C[8];
    int lda[8], ldb[8], ldc[8], K[8], N[8];
    int tstart[9]; int ne;
};

__global__ __launch_bounds__(128) void gemm_multi(MG8 mg)
{
    int bx = blockIdx.x;
    int e = 0;
    for (int i = 1; i < mg.ne; ++i) if (bx >= mg.tstart[i]) e = i;
    const float* A = mg.A[e];
    const float* B = mg.B[e];
    float* C = mg.C[e];
    int lda = mg.lda[e], ldb = mg.ldb[e], ldc = mg.ldc[e];
    int K = mg.K[e], N = mg.N[e];
    int m0 = blockIdx.y * 32, n0 = (bx - mg.tstart[e]) * 64;

    __shared__ float As[16][36];
    __shared__ float Bs[16][68];
    int t = threadIdx.x;
    int am = t >> 2, ak = t & 3;     // A: row am (0..31), k-quad ak (0..3)
    int bk = t >> 3, bn = t & 7;     // B: k-row bk (0..15), f4-cols bn, bn+8
    int ty = t >> 4, tx = t & 15;    // compute: rows ty*4.., cols tx*4..
    bool ok0 = (n0 + bn * 4) < N;
    bool ok1 = (n0 + (bn + 8) * 4) < N;

    float4 aN = *(const float4*)(A + (long)(m0 + am) * lda + ak * 4);
    float4 b0 = ok0 ? *(const float4*)(B + (long)bk * ldb + n0 + bn * 4)
                    : make_float4(0.f, 0.f, 0.f, 0.f);
    float4 b1 = ok1 ? *(const float4*)(B + (long)bk * ldb + n0 + (bn + 8) * 4)
                    : make_float4(0.f, 0.f, 0.f, 0.f);
    float acc[4][4] = {};
    for (int k0 = 0; k0 < K; k0 += 16) {
        As[ak * 4 + 0][am] = aN.x;
        As[ak * 4 + 1][am] = aN.y;
        As[ak * 4 + 2][am] = aN.z;
        As[ak * 4 + 3][am] = aN.w;
        *(float4*)&Bs[bk][bn * 4] = b0;
        *(float4*)&Bs[bk][(bn + 8) * 4] = b1;
        __syncthreads();
        if (k0 + 16 < K) {
            aN = *(const float4*)(A + (long)(m0 + am) * lda + (k0 + 16) + ak * 4);
            b0 = ok0 ? *(const float4*)(B + (long)(k0 + 16 + bk) * ldb + n0 + bn * 4)
                     : make_float4(0.f, 0.f, 0.f, 0.f);
            b1 = ok1 ? *(const float4*)(B + (long)(k0 + 16 + bk) * ldb + n0 + (bn + 8) * 4)
                     : make_float4(0.f, 0.f, 0.f, 0.f);
        }
        #pragma unroll
        for (int kk = 0; kk < 16; ++kk) {
            float4 a = *(float4*)&As[kk][ty * 4];
            float4 b = *(float4*)&Bs[kk][tx * 4];
            acc[0][0] += a.x * b.x; acc[0][1] += a.x * b.y; acc[0][2] += a.x * b.z; acc[0][3] += a.x * b.w;
            acc[1][0] += a.y * b.x; acc[1][1] += a.y * b.y; acc[1][2] += a.y * b.z; acc[1][3] += a.y * b.w;
            acc[2][0] += a.z * b.x; acc[2][1] += a.z * b.y; acc[2][2] += a.z * b.z; acc[2][3] += a.z * b.w;
            acc[3][0] += a.w * b.x; acc[3][1] += a.w * b.y; acc[3][2] += a.w * b.z; acc[3][3] += a.w * b.w;
        }
        __syncthreads();
    }
    if ((n0 + tx * 4) < N) {
        #pragma unroll
        for (int i = 0; i < 4; ++i) {
            float4 v = make_float4(acc[i][0], acc[i][1], acc[i][2], acc[i][3]);
            *(float4*)(C + (long)(m0 + ty * 4 + i) * ldc + n0 + tx * 4) = v;
        }
    }
}

// ---------------- PoPE for queries: pre (1024 x 256) -> out (1024 x [h][32]) --
__global__ __launch_bounds__(128) void pope_q_kernel(
    const float* __restrict__ pre, const float* __restrict__ raw_delta,
    float* __restrict__ outq)
{
    int t = blockIdx.x, tid = threadIdx.x;
    int h = tid >> 4, i = tid & 15;
    float rd = raw_delta[i];
    float delta = -6.283185307179586f * (1.f / (1.f + expf(-rd)));
    float th = exp2f(-(float)i * 0.83048202372184f);   // 10000^(-i/16)
    float ang = (float)t * th + delta;
    float sv, cv;
    sincosf(ang, &sv, &cv);
    float m1 = sp_softplus(pre[t * 256 + h * 32 + i]);
    float m2 = sp_softplus(pre[t * 256 + h * 32 + 16 + i]);
    outq[t * 256 + h * 32 + i]      = m1 * cv - m2 * sv;
    outq[t * 256 + h * 32 + 16 + i] = m1 * sv + m2 * cv;
}

// -------- prep: mu = softplus(xkr) (32768) + key-PoPE cos/sin table (2048) ---
__global__ __launch_bounds__(256) void prep_kernel(
    const float* __restrict__ xkr, const float* __restrict__ raw_delta,
    float* __restrict__ mu, float* __restrict__ csc, float* __restrict__ css)
{
    int b = blockIdx.x, tid = threadIdx.x;
    if (b < 128) {
        int i = b * 256 + tid;
        mu[i] = sp_softplus(xkr[i]);
    } else {
        int idx = (b - 128) * 256 + tid;    // 0..2047
        int j = idx >> 4, i = idx & 15;
        float rd = raw_delta[i];
        float delta = -6.283185307179586f * (1.f / (1.f + expf(-rd)));
        float th = exp2f(-(float)i * 0.83048202372184f);
        float ang = (float)j * th + delta;
        float sv, cv;
        sincosf(ang, &sv, &cv);
        csc[idx] = cv;
        css[idx] = sv;
    }
}

// -------- absorbed query: qabs[t][h][c] = sum_d qc[t, h*64+d] * w_uk[c, h*64+d]
__global__ __launch_bounds__(256) void qabs_kernel(
    const float* __restrict__ qc, const float* __restrict__ w_uk,
    float* __restrict__ qabs)
{
    int h = blockIdx.x;
    int t0 = blockIdx.y * 16;
    __shared__ float qcs[16][65];
    __shared__ float wks[16][65];
    int tid = threadIdx.x;
    {
        int r = tid >> 6, d = tid & 63;
        #pragma unroll
        for (int u = 0; u < 4; ++u)
            qcs[r + u * 4][d] = qc[(long)(t0 + r + u * 4) * 512 + h * 64 + d];
    }
    int tt = tid >> 4, cc = tid & 15;
    for (int c0 = 0; c0 < 256; c0 += 16) {
        __syncthreads();
        {
            int r = tid >> 6, d = tid & 63;
            #pragma unroll
            for (int u = 0; u < 4; ++u)
                wks[r + u * 4][d] = w_uk[(long)(c0 + r + u * 4) * 512 + h * 64 + d];
        }
        __syncthreads();
        float acc = 0.f, acc2 = 0.f;
        #pragma unroll
        for (int d = 0; d < 64; d += 2) {
            acc  += qcs[tt][d]     * wks[cc][d];
            acc2 += qcs[tt][d + 1] * wks[cc][d + 1];
        }
        qabs[(long)(t0 + tt) * 2048 + h * 256 + c0 + cc] = acc + acc2;
    }
}

// -------- lightning indexer: I[t][s] = sum_h w_idx[h]*relu(qI[t,h,:].kI[s,:]) --
__global__ __launch_bounds__(256) void indexer_kernel(
    const float* __restrict__ qI, const float* __restrict__ kI,
    const float* __restrict__ w_idx, float* __restrict__ I)
{
    int sb = blockIdx.x, tb = blockIdx.y;
    if (sb > tb) return;
    int t0 = tb * 64, s0 = sb * 64;
    __shared__ float qs[64][65];
    __shared__ float ks[64][65];
    int tid = threadIdx.x;
    int ty = tid >> 4, tx = tid & 15;
    {
        int rr = tid >> 6, d = tid & 63;
        #pragma unroll
        for (int u = 0; u < 16; ++u)
            ks[rr * 16 + u][d] = kI[(long)(s0 + rr * 16 + u) * 64 + d];
    }
    float accI[4][4] = {};
    for (int h = 0; h < 8; ++h) {
        __syncthreads();
        {
            int rr = tid >> 6, d = tid & 63;
            #pragma unroll
            for (int u = 0; u < 16; ++u)
                qs[rr * 16 + u][d] = qI[(long)(t0 + rr * 16 + u) * 512 + h * 64 + d];
        }
        __syncthreads();
        float acc[4][4] = {};
        #pragma unroll 8
        for (int d = 0; d < 64; ++d) {
            float a[4], b[4];
            #pragma unroll
            for (int i = 0; i < 4; ++i) a[i] = qs[ty * 4 + i][d];
            #pragma unroll
            for (int j = 0; j < 4; ++j) b[j] = ks[tx * 4 + j][d];
            #pragma unroll
            for (int i = 0; i < 4; ++i)
                #pragma unroll
                for (int j = 0; j < 4; ++j) acc[i][j] += a[i] * b[j];
        }
        float wh = w_idx[h];
        #pragma unroll
        for (int i = 0; i < 4; ++i)
            #pragma unroll
            for (int j = 0; j < 4; ++j)
                accI[i][j] += wh * fmaxf(acc[i][j], 0.f);
    }
    #pragma unroll
    for (int i = 0; i < 4; ++i) {
        float4 v = make_float4(accI[i][0], accI[i][1], accI[i][2], accI[i][3]);
        *(float4*)&I[(long)(t0 + ty * 4 + i) * 1024 + s0 + tx * 4] = v;
    }
}

// -------- exact top-k (jax.lax.top_k semantics: value desc, ties index asc) ---
__global__ __launch_bounds__(256) void topk_kernel(
    const float* __restrict__ I, int* __restrict__ idxout)
{
    int t = blockIdx.x * 4 + (threadIdx.x >> 6);
    int lane = threadIdx.x & 63;
    int smin = max(0, t - 63);
    int w = min(64, t + 1);
    if (lane < w) idxout[t * 128 + lane] = smin + lane;
    for (int q = t + 1 + lane; q < 128; q += 64)
        idxout[t * 128 + q] = q;
    int f = max(0, t - 63);
    int m = min(f, 64);
    if (m == 0) return;
    const float* row = I + (long)t * 1024;
    unsigned long long key[16];
    #pragma unroll
    for (int i = 0; i < 16; ++i) {
        int s = i * 64 + lane;
        key[i] = 0ull;
        if (s < f) {
            unsigned u = __float_as_uint(row[s]);
            unsigned ou = (u & 0x80000000u) ? ~u : (u | 0x80000000u);
            key[i] = ((unsigned long long)ou << 32) | (0xFFFFFFFFu - (unsigned)s);
        }
    }
    for (int it = 0; it < m; ++it) {
        unsigned long long best = key[0];
        #pragma unroll
        for (int i = 1; i < 16; ++i) best = key[i] > best ? key[i] : best;
        #pragma unroll
        for (int off = 32; off > 0; off >>= 1) {
            unsigned long long o = __shfl_xor(best, off, 64);
            best = o > best ? o : best;
        }
        int s = (int)(0xFFFFFFFFu - (unsigned)(best & 0xFFFFFFFFull));
        if (lane == 0) idxout[t * 128 + w + it] = s;
        if ((s & 63) == lane) {
            int slot = s >> 6;
            #pragma unroll
            for (int i = 0; i < 16; ++i)
                if (i == slot) key[i] = 0ull;
        }
    }
}

// -------- fused attention v3: flash-style, row-major LDS, float4 everywhere ---
// block per query t, 512 threads (wave = head). LDS ~47.6 KB -> 3 blocks/CU.
__global__ __launch_bounds__(512) void attn_kernel(
    const float* __restrict__ qabs, const float* __restrict__ qrr,
    const float* __restrict__ ckv, const float* __restrict__ mu,
    const float* __restrict__ csc, const float* __restrict__ css,
    const int* __restrict__ idxb, float* __restrict__ olat)
{
    __shared__ float ckv_s[32 * 260];   // row-major [j][c], stride 260 (65 f4)
    __shared__ float kr_s[32 * 36];     // row-major [j][i], stride 36 (9 f4)
    __shared__ float qa_s[8 * 256];
    __shared__ float qr_s[8 * 32];
    __shared__ int   idx_s[128];

    int t = blockIdx.x, tid = threadIdx.x;
    int h = tid >> 6, l = tid & 63;
    const float scale = 0.10206207261596575f;   // (64+32)^-0.5

    if (tid < 128) idx_s[tid] = idxb[t * 128 + tid];
    {
        float4 v = ((const float4*)(qabs + (long)t * 2048))[tid];
        v.x *= scale; v.y *= scale; v.z *= scale; v.w *= scale;
        ((float4*)qa_s)[tid] = v;
    }
    if (tid < 64) {
        float4 v = ((const float4*)(qrr + (long)t * 256))[tid];
        v.x *= scale; v.y *= scale; v.z *= scale; v.w *= scale;
        ((float4*)qr_s)[tid] = v;
    }
    __syncthreads();

    float m_run = -INFINITY, l_run = 0.f;
    float4 acc = make_float4(0.f, 0.f, 0.f, 0.f);
    int jq = l & 31, ch = l >> 5;
    int sr = tid >> 4, sq = tid & 15;   // staging: row sr (0..31), f4 group sq

    for (int chunk = 0; chunk < 4; ++chunk) {
        int j0 = chunk * 32;
        {   // stage 32 gathered ckv rows, row-major; 4 consecutive f4/thread
            int src = idx_s[j0 + sr];
            const float4* sp4 = (const float4*)(ckv + (long)src * 256);
            float4* dst = (float4*)(ckv_s + sr * 260);
            #pragma unroll
            for (int u = 0; u < 4; ++u) dst[sq * 4 + u] = sp4[sq * 4 + u];
        }
        {   // stage kr rows: kr[j][i] = PoPE(mu[src], pos = j0+j)
            int src = idx_s[j0 + sr];
            float m1 = mu[src * 32 + sq];
            float m2 = mu[src * 32 + 16 + sq];
            float cv = csc[(j0 + sr) * 16 + sq];
            float sv = css[(j0 + sr) * 16 + sq];
            kr_s[sr * 36 + sq]      = m1 * cv - m2 * sv;
            kr_s[sr * 36 + 16 + sq] = m1 * sv + m2 * cv;
        }
        __syncthreads();

        // QK: lane (jq, ch) dots its c-half of row jq
        float S = 0.f;
        {
            const float* qa = qa_s + h * 256 + ch * 128;
            const float* cb = ckv_s + jq * 260 + ch * 128;
            #pragma unroll 8
            for (int c4 = 0; c4 < 32; ++c4) {
                float4 q4 = *(const float4*)(qa + c4 * 4);
                float4 k4 = *(const float4*)(cb + c4 * 4);
                S += q4.x * k4.x + q4.y * k4.y + q4.z * k4.z + q4.w * k4.w;
            }
            const float* qr = qr_s + h * 32 + ch * 16;
            const float* kb = kr_s + jq * 36 + ch * 16;
            #pragma unroll
            for (int i4 = 0; i4 < 4; ++i4) {
                float4 q4 = *(const float4*)(qr + i4 * 4);
                float4 k4 = *(const float4*)(kb + i4 * 4);
                S += q4.x * k4.x + q4.y * k4.y + q4.z * k4.z + q4.w * k4.w;
            }
        }
        S += __shfl_xor(S, 32);   // combine c-halves (both halves now identical)

        // online softmax within each 32-lane half (values distinct over jq)
        float mx = S;
        #pragma unroll
        for (int off = 16; off > 0; off >>= 1) mx = fmaxf(mx, __shfl_xor(mx, off));
        float m_new = fmaxf(m_run, mx);
        float r = expf(m_run - m_new);
        float p = expf(S - m_new);
        float ps = p;
        #pragma unroll
        for (int off = 16; off > 0; off >>= 1) ps += __shfl_xor(ps, off);
        l_run = l_run * r + ps;
        m_run = m_new;
        acc.x *= r; acc.y *= r; acc.z *= r; acc.w *= r;

        // PV: lane owns c-quad [l*4, l*4+4); p[j] broadcast via shuffle
        {
            const float* cb = ckv_s + l * 4;
            #pragma unroll 8
            for (int j = 0; j < 32; ++j) {
                float pj = __shfl(p, j);
                float4 v4 = *(const float4*)(cb + j * 260);
                acc.x += pj * v4.x; acc.y += pj * v4.y;
                acc.z += pj * v4.z; acc.w += pj * v4.w;
            }
        }
        __syncthreads();
    }

    float inv = 1.f / l_run;
    float4 o = make_float4(acc.x * inv, acc.y * inv, acc.z * inv, acc.w * inv);
    *(float4*)(olat + (long)t * 2048 + h * 256 + l * 4) = o;
}

extern "C" void kernel_launch(void* const* d_in, const int* in_sizes, int n_in,
                              void* d_out, int out_size, void* d_ws, size_t ws_size,
                              hipStream_t stream)
{
    const float* x         = (const float*)d_in[0];
    const float* w_q_idx   = (const float*)d_in[1];
    const float* w_k_idx   = (const float*)d_in[2];
    const float* w_idx     = (const float*)d_in[3];
    const float* raw_delta = (const float*)d_in[4];
    const float* w_dkv     = (const float*)d_in[5];
    const float* w_uk      = (const float*)d_in[6];
    const float* w_uv      = (const float*)d_in[7];
    const float* w_dq      = (const float*)d_in[8];
    const float* w_uq      = (const float*)d_in[9];
    const float* w_qr      = (const float*)d_in[10];
    const float* w_kr      = (const float*)d_in[11];
    const float* w_out     = (const float*)d_in[12];
    (void)in_sizes; (void)n_in; (void)out_size; (void)ws_size;
    float* out = (float*)d_out;

    float* ws = (float*)d_ws;
    float* qI   = ws;        ws += 1024 * 512;
    float* kI   = ws;        ws += 1024 * 64;
    float* ckv  = ws;        ws += 1024 * 256;
    float* cq   = ws;        ws += 1024 * 512;
    float* xkr  = ws;        ws += 1024 * 32;
    float* qrp  = ws;        ws += 1024 * 256;
    float* qrr  = ws;        ws += 1024 * 256;
    float* qc   = ws;        ws += 1024 * 512;
    float* qabs = ws;        ws += 1024 * 2048;
    float* Ibuf = ws;        ws += 1024 * 1024;
    int*   idxb = (int*)ws;  ws += 1024 * 128;
    float* olat = ws;        ws += 1024 * 2048;
    float* outh = ws;        ws += 1024 * 512;
    float* mu   = ws;        ws += 1024 * 32;
    float* cscb = ws;        ws += 128 * 16;
    float* cssb = ws;        ws += 128 * 16;

    // ---- stage 1: all five x-projections in one launch
    MG8 s1{};
    for (int i = 0; i < 5; ++i) { s1.A[i] = x; s1.lda[i] = 1024; s1.K[i] = 1024; }
    s1.B[0] = w_q_idx; s1.C[0] = qI;  s1.ldb[0] = 512; s1.ldc[0] = 512; s1.N[0] = 512;
    s1.B[1] = w_k_idx; s1.C[1] = kI;  s1.ldb[1] = 64;  s1.ldc[1] = 64;  s1.N[1] = 64;
    s1.B[2] = w_dkv;   s1.C[2] = ckv; s1.ldb[2] = 256; s1.ldc[2] = 256; s1.N[2] = 256;
    s1.B[3] = w_dq;    s1.C[3] = cq;  s1.ldb[3] = 512; s1.ldc[3] = 512; s1.N[3] = 512;
    s1.B[4] = w_kr;    s1.C[4] = xkr; s1.ldb[4] = 32;  s1.ldc[4] = 32;  s1.N[4] = 32;
    int t1[6] = {0, 8, 9, 13, 21, 22};
    for (int i = 0; i < 6; ++i) s1.tstart[i] = t1[i];
    s1.ne = 5;
    gemm_multi<<<dim3(22, 32), dim3(128), 0, stream>>>(s1);

    prep_kernel<<<dim3(136), dim3(256), 0, stream>>>(xkr, raw_delta, mu, cscb, cssb);

    // ---- stage 2: both c_q projections
    MG8 s2{};
    for (int i = 0; i < 2; ++i) { s2.A[i] = cq; s2.lda[i] = 512; s2.K[i] = 512; }
    s2.B[0] = w_uq; s2.C[0] = qc;  s2.ldb[0] = 512; s2.ldc[0] = 512; s2.N[0] = 512;
    s2.B[1] = w_qr; s2.C[1] = qrp; s2.ldb[1] = 256; s2.ldc[1] = 256; s2.N[1] = 256;
    s2.tstart[0] = 0; s2.tstart[1] = 8; s2.tstart[2] = 12;
    s2.ne = 2;
    gemm_multi<<<dim3(12, 32), dim3(128), 0, stream>>>(s2);

    pope_q_kernel<<<dim3(1024), dim3(128), 0, stream>>>(qrp, raw_delta, qrr);
    qabs_kernel<<<dim3(8, 64), dim3(256), 0, stream>>>(qc, w_uk, qabs);

    // ---- indexer + exact top-k (bitwise-stable selection path)
    indexer_kernel<<<dim3(16, 16), dim3(256), 0, stream>>>(qI, kI, w_idx, Ibuf);
    topk_kernel<<<dim3(256), dim3(256), 0, stream>>>(Ibuf, idxb);

    // ---- fused attention -> latent output
    attn_kernel<<<dim3(1024), dim3(512), 0, stream>>>(qabs, qrr, ckv, mu, cscb, cssb, idxb, olat);

    // ---- o_lat @ w_uv (8 heads, one launch)
    MG8 s3{};
    for (int h = 0; h < 8; ++h) {
        s3.A[h] = olat + h * 256; s3.lda[h] = 2048; s3.K[h] = 256;
        s3.B[h] = w_uv + h * 64;  s3.ldb[h] = 512;
        s3.C[h] = outh + h * 64;  s3.ldc[h] = 512;  s3.N[h] = 64;
        s3.tstart[h] = h;
    }
    s3.tstart[8] = 8;
    s3.ne = 8;
    gemm_multi<<<dim3(8, 32), dim3(128), 0, stream>>>(s3);

    // ---- final: outh @ w_out
    MG8 s4{};
    s4.A[0] = outh; s4.lda[0] = 512; s4.K[0] = 512;
    s4.B[0] = w_out; s4.ldb[0] = 1024;
    s4.C[0] = out;   s4.ldc[0] = 1024; s4.N[0] = 1024;
    s4.tstart[0] = 0; s4.tstart[1] = 16;
    s4.ne = 1;
    gemm_multi<<<dim3(16, 32), dim3(128), 0, stream>>>(s4);
}

// Round 5
// 302.483 us; speedup vs baseline: 2.6022x; 1.0205x over previous
//
#include <hip/hip_runtime.h>
#include <math.h>

#define S_LEN 1024
#define NH 8

__device__ __forceinline__ float sp_softplus(float x) {
    return fmaxf(x, 0.f) + log1pf(expf(-fabsf(x)));
}

// ============ routed multi-GEMM with optional deterministic split-K =========
// BM=16, BN=64, BK=16, 128 threads, 2x4 microtile. Per entry e:
//   C_e[1024, N_e] = A_e[1024, K_e] @ B_e[K_e, N_e]
// units per entry = ntiles(N)*KS; unit -> (ntile, ks). KS>1 writes compact
// partial slab Cw + ks*pstride (ldc = N); reduce_k sums ks-ascending (exact
// deterministic order). Selection-path entries use KS=1 and preserve the
// per-output k-ascending fmac chain bit-for-bit (absmax canary).
struct MGK {
    const float* A[10]; const float* B[10]; float* Cw[10];
    int lda[10], ldb[10], wldc[10], K[10], N[10], KS[10], ntiles[10];
    long pstride[10];
    int ustart[11]; int ne;
};

__global__ __launch_bounds__(128) void gemmk(MGK mg)
{
    int u = blockIdx.x;
    int e = 0;
    #pragma unroll
    for (int i = 1; i < 10; ++i) if (i < mg.ne && u >= mg.ustart[i]) e = i;
    int local = u - mg.ustart[e];
    int nt = local % mg.ntiles[e];
    int ks = local / mg.ntiles[e];
    const float* A = mg.A[e];
    const float* B = mg.B[e];
    int lda = mg.lda[e], ldb = mg.ldb[e], ldc = mg.wldc[e];
    int N = mg.N[e];
    int kb = ks * (mg.K[e] / mg.KS[e]);
    int ke = kb + mg.K[e] / mg.KS[e];
    float* C = mg.Cw[e] + ks * mg.pstride[e];
    int m0 = blockIdx.y * 16, n0 = nt * 64;

    __shared__ float As[16][18];
    __shared__ float Bs[16][68];
    int t = threadIdx.x;
    int ar = t >> 2, ak = t & 3;     // A staging (threads < 64)
    int bk = t >> 3, bn = t & 7;     // B staging
    int ty = t >> 4, tx = t & 15;    // compute: rows ty*2.., cols tx*4..
    bool ok0 = (n0 + bn * 4) < N;
    bool ok1 = (n0 + (bn + 8) * 4) < N;

    float4 aN = make_float4(0.f, 0.f, 0.f, 0.f);
    if (t < 64) aN = *(const float4*)(A + (long)(m0 + ar) * lda + kb + ak * 4);
    float4 b0 = ok0 ? *(const float4*)(B + (long)kb * ldb + (long)bk * ldb + n0 + bn * 4)
                    : make_float4(0.f, 0.f, 0.f, 0.f);
    float4 b1 = ok1 ? *(const float4*)(B + (long)kb * ldb + (long)bk * ldb + n0 + (bn + 8) * 4)
                    : make_float4(0.f, 0.f, 0.f, 0.f);
    float acc[2][4] = {};
    for (int k0 = kb; k0 < ke; k0 += 16) {
        if (t < 64) {
            As[ak * 4 + 0][ar] = aN.x;
            As[ak * 4 + 1][ar] = aN.y;
            As[ak * 4 + 2][ar] = aN.z;
            As[ak * 4 + 3][ar] = aN.w;
        }
        *(float4*)&Bs[bk][bn * 4] = b0;
        *(float4*)&Bs[bk][(bn + 8) * 4] = b1;
        __syncthreads();
        if (k0 + 16 < ke) {
            if (t < 64) aN = *(const float4*)(A + (long)(m0 + ar) * lda + (k0 + 16) + ak * 4);
            b0 = ok0 ? *(const float4*)(B + (long)(k0 + 16 + bk) * ldb + n0 + bn * 4)
                     : make_float4(0.f, 0.f, 0.f, 0.f);
            b1 = ok1 ? *(const float4*)(B + (long)(k0 + 16 + bk) * ldb + n0 + (bn + 8) * 4)
                     : make_float4(0.f, 0.f, 0.f, 0.f);
        }
        #pragma unroll
        for (int kk = 0; kk < 16; ++kk) {
            float2 a = *(float2*)&As[kk][ty * 2];
            float4 b = *(float4*)&Bs[kk][tx * 4];
            acc[0][0] += a.x * b.x; acc[0][1] += a.x * b.y;
            acc[0][2] += a.x * b.z; acc[0][3] += a.x * b.w;
            acc[1][0] += a.y * b.x; acc[1][1] += a.y * b.y;
            acc[1][2] += a.y * b.z; acc[1][3] += a.y * b.w;
        }
        __syncthreads();
    }
    if ((n0 + tx * 4) < N) {
        #pragma unroll
        for (int i = 0; i < 2; ++i) {
            float4 v = make_float4(acc[i][0], acc[i][1], acc[i][2], acc[i][3]);
            *(float4*)(C + (long)(m0 + ty * 2 + i) * ldc + n0 + tx * 4) = v;
        }
    }
}

// ---- deterministic split-K reduce: dst[r][c] = sum_ks src[ks*slab + i] -----
struct RED8 {
    const float4* src[8]; float4* dst[8];
    long slab[8]; int ks[8], cshift[8], lddst[8];
    int bstart[9]; int ne;
};
__global__ __launch_bounds__(256) void reduce_k(RED8 rd)
{
    int b = blockIdx.x;
    int e = 0;
    #pragma unroll
    for (int i = 1; i < 8; ++i) if (i < rd.ne && b >= rd.bstart[i]) e = i;
    long i = (long)(b - rd.bstart[e]) * 256 + threadIdx.x;
    int cmask = (1 << rd.cshift[e]) - 1;
    long r = i >> rd.cshift[e];
    int c = (int)(i & cmask);
    const float4* s = rd.src[e];
    float4 a = s[i];
    for (int k = 1; k < rd.ks[e]; ++k) {
        float4 v = s[(long)k * rd.slab[e] + i];
        a.x += v.x; a.y += v.y; a.z += v.z; a.w += v.w;
    }
    rd.dst[e][r * rd.lddst[e] + c] = a;
}

// ---- prep: mu = softplus(xkr); key-PoPE cos/sin table; w_ukT transpose -----
__global__ __launch_bounds__(256) void prep_kernel(
    const float* __restrict__ xkr, const float* __restrict__ raw_delta,
    const float* __restrict__ w_uk,
    float* __restrict__ mu, float* __restrict__ csc, float* __restrict__ css,
    float* __restrict__ w_ukT)
{
    int b = blockIdx.x, tid = threadIdx.x;
    if (b < 128) {
        int i = b * 256 + tid;
        mu[i] = sp_softplus(xkr[i]);
    } else if (b < 136) {
        int idx = (b - 128) * 256 + tid;    // 0..2047
        int j = idx >> 4, i = idx & 15;
        float rd = raw_delta[i];
        float delta = -6.283185307179586f * (1.f / (1.f + expf(-rd)));
        float th = exp2f(-(float)i * 0.83048202372184f);
        float ang = (float)j * th + delta;
        float sv, cv;
        sincosf(ang, &sv, &cv);
        csc[idx] = cv;
        css[idx] = sv;
    } else {
        int idx = (b - 136) * 256 + tid;    // 0..131071 ; w_ukT[d][c]
        int d = idx >> 8, c = idx & 255;
        w_ukT[idx] = w_uk[c * 512 + d];
    }
}

// ---------------- PoPE for queries (bitwise-unchanged) ------------------------
__global__ __launch_bounds__(128) void pope_q_kernel(
    const float* __restrict__ pre, const float* __restrict__ raw_delta,
    float* __restrict__ outq)
{
    int t = blockIdx.x, tid = threadIdx.x;
    int h = tid >> 4, i = tid & 15;
    float rd = raw_delta[i];
    float delta = -6.283185307179586f * (1.f / (1.f + expf(-rd)));
    float th = exp2f(-(float)i * 0.83048202372184f);
    float ang = (float)t * th + delta;
    float sv, cv;
    sincosf(ang, &sv, &cv);
    float m1 = sp_softplus(pre[t * 256 + h * 32 + i]);
    float m2 = sp_softplus(pre[t * 256 + h * 32 + 16 + i]);
    outq[t * 256 + h * 32 + i]      = m1 * cv - m2 * sv;
    outq[t * 256 + h * 32 + 16 + i] = m1 * sv + m2 * cv;
}

// -------- lightning indexer v2: 32-row tiles, ksT-transposed LDS, f4 reads ---
// Per-output arithmetic bit-identical to v1: for h ascending, d 0..63 ascending
// fmac chain from zero, then accI += w_h * relu(acc).
__global__ __launch_bounds__(256) void indexer_kernel(
    const float* __restrict__ qI, const float* __restrict__ kI,
    const float* __restrict__ w_idx, float* __restrict__ I)
{
    int sb = blockIdx.x, tb = blockIdx.y;
    if (sb * 64 > tb * 32 + 31) return;
    int t0 = tb * 32, s0 = sb * 64;
    __shared__ float ksT[64][68];   // [d][s-local]
    __shared__ float qs[32][68];    // [t-local][d]
    int t = threadIdx.x;
    {   // stage ksT transposed: 64 rows x 16 f4
        int r = t & 63, q = t >> 6;
        #pragma unroll
        for (int u = 0; u < 4; ++u) {
            int c4 = q * 4 + u;
            float4 v = *(const float4*)(kI + (long)(s0 + r) * 64 + c4 * 4);
            ksT[c4 * 4 + 0][r] = v.x;
            ksT[c4 * 4 + 1][r] = v.y;
            ksT[c4 * 4 + 2][r] = v.z;
            ksT[c4 * 4 + 3][r] = v.w;
        }
    }
    int ty = t >> 4, tx = t & 15;
    float accI[2][4] = {};
    for (int h = 0; h < 8; ++h) {
        __syncthreads();
        {   // stage qs rows for head h
            int r = t >> 3, q = t & 7;
            *(float4*)&qs[r][q * 4] =
                *(const float4*)(qI + (long)(t0 + r) * 512 + h * 64 + q * 4);
            *(float4*)&qs[r][(q + 8) * 4] =
                *(const float4*)(qI + (long)(t0 + r) * 512 + h * 64 + (q + 8) * 4);
        }
        __syncthreads();
        float acc[2][4] = {};
        #pragma unroll
        for (int dc = 0; dc < 4; ++dc) {
            float a0[16], a1[16];
            #pragma unroll
            for (int u = 0; u < 4; ++u) {
                float4 v0 = *(float4*)&qs[ty * 2][dc * 16 + u * 4];
                float4 v1 = *(float4*)&qs[ty * 2 + 1][dc * 16 + u * 4];
                a0[u * 4 + 0] = v0.x; a0[u * 4 + 1] = v0.y; a0[u * 4 + 2] = v0.z; a0[u * 4 + 3] = v0.w;
                a1[u * 4 + 0] = v1.x; a1[u * 4 + 1] = v1.y; a1[u * 4 + 2] = v1.z; a1[u * 4 + 3] = v1.w;
            }
            #pragma unroll
            for (int kk = 0; kk < 16; ++kk) {
                int d = dc * 16 + kk;
                float4 b = *(float4*)&ksT[d][tx * 4];
                acc[0][0] += a0[kk] * b.x; acc[0][1] += a0[kk] * b.y;
                acc[0][2] += a0[kk] * b.z; acc[0][3] += a0[kk] * b.w;
                acc[1][0] += a1[kk] * b.x; acc[1][1] += a1[kk] * b.y;
                acc[1][2] += a1[kk] * b.z; acc[1][3] += a1[kk] * b.w;
            }
        }
        float wh = w_idx[h];
        #pragma unroll
        for (int i = 0; i < 2; ++i)
            #pragma unroll
            for (int j = 0; j < 4; ++j)
                accI[i][j] += wh * fmaxf(acc[i][j], 0.f);
    }
    #pragma unroll
    for (int i = 0; i < 2; ++i) {
        float4 v = make_float4(accI[i][0], accI[i][1], accI[i][2], accI[i][3]);
        *(float4*)&I[(long)(t0 + ty * 2 + i) * 1024 + s0 + tx * 4] = v;
    }
}

// -------- exact top-k (unchanged, bitwise) -----------------------------------
__global__ __launch_bounds__(256) void topk_kernel(
    const float* __restrict__ I, int* __restrict__ idxout)
{
    int t = blockIdx.x * 4 + (threadIdx.x >> 6);
    int lane = threadIdx.x & 63;
    int smin = max(0, t - 63);
    int w = min(64, t + 1);
    if (lane < w) idxout[t * 128 + lane] = smin + lane;
    for (int q = t + 1 + lane; q < 128; q += 64)
        idxout[t * 128 + q] = q;
    int f = max(0, t - 63);
    int m = min(f, 64);
    if (m == 0) return;
    const float* row = I + (long)t * 1024;
    unsigned long long key[16];
    #pragma unroll
    for (int i = 0; i < 16; ++i) {
        int s = i * 64 + lane;
        key[i] = 0ull;
        if (s < f) {
            unsigned u = __float_as_uint(row[s]);
            unsigned ou = (u & 0x80000000u) ? ~u : (u | 0x80000000u);
            key[i] = ((unsigned long long)ou << 32) | (0xFFFFFFFFu - (unsigned)s);
        }
    }
    for (int it = 0; it < m; ++it) {
        unsigned long long best = key[0];
        #pragma unroll
        for (int i = 1; i < 16; ++i) best = key[i] > best ? key[i] : best;
        #pragma unroll
        for (int off = 32; off > 0; off >>= 1) {
            unsigned long long o = __shfl_xor(best, off, 64);
            best = o > best ? o : best;
        }
        int s = (int)(0xFFFFFFFFu - (unsigned)(best & 0xFFFFFFFFull));
        if (lane == 0) idxout[t * 128 + w + it] = s;
        if ((s & 63) == lane) {
            int slot = s >> 6;
            #pragma unroll
            for (int i = 0; i < 16; ++i)
                if (i == slot) key[i] = 0ull;
        }
    }
}

// -------- fused attention (unchanged from r4, bitwise) ------------------------
__global__ __launch_bounds__(512) void attn_kernel(
    const float* __restrict__ qabs, const float* __restrict__ qrr,
    const float* __restrict__ ckv, const float* __restrict__ mu,
    const float* __restrict__ csc, const float* __restrict__ css,
    const int* __restrict__ idxb, float* __restrict__ olat)
{
    __shared__ float ckv_s[32 * 260];
    __shared__ float kr_s[32 * 36];
    __shared__ float qa_s[8 * 256];
    __shared__ float qr_s[8 * 32];
    __shared__ int   idx_s[128];

    int t = blockIdx.x, tid = threadIdx.x;
    int h = tid >> 6, l = tid & 63;
    const float scale = 0.10206207261596575f;

    if (tid < 128) idx_s[tid] = idxb[t * 128 + tid];
    {
        float4 v = ((const float4*)(qabs + (long)t * 2048))[tid];
        v.x *= scale; v.y *= scale; v.z *= scale; v.w *= scale;
        ((float4*)qa_s)[tid] = v;
    }
    if (tid < 64) {
        float4 v = ((const float4*)(qrr + (long)t * 256))[tid];
        v.x *= scale; v.y *= scale; v.z *= scale; v.w *= scale;
        ((float4*)qr_s)[tid] = v;
    }
    __syncthreads();

    float m_run = -INFINITY, l_run = 0.f;
    float4 acc = make_float4(0.f, 0.f, 0.f, 0.f);
    int jq = l & 31, ch = l >> 5;
    int sr = tid >> 4, sq = tid & 15;

    for (int chunk = 0; chunk < 4; ++chunk) {
        int j0 = chunk * 32;
        {
            int src = idx_s[j0 + sr];
            const float4* sp4 = (const float4*)(ckv + (long)src * 256);
            float4* dst = (float4*)(ckv_s + sr * 260);
            #pragma unroll
            for (int u = 0; u < 4; ++u) dst[sq * 4 + u] = sp4[sq * 4 + u];
        }
        {
            int src = idx_s[j0 + sr];
            float m1 = mu[src * 32 + sq];
            float m2 = mu[src * 32 + 16 + sq];
            float cv = csc[(j0 + sr) * 16 + sq];
            float sv = css[(j0 + sr) * 16 + sq];
            kr_s[sr * 36 + sq]      = m1 * cv - m2 * sv;
            kr_s[sr * 36 + 16 + sq] = m1 * sv + m2 * cv;
        }
        __syncthreads();

        float S = 0.f;
        {
            const float* qa = qa_s + h * 256 + ch * 128;
            const float* cb = ckv_s + jq * 260 + ch * 128;
            #pragma unroll 8
            for (int c4 = 0; c4 < 32; ++c4) {
                float4 q4 = *(const float4*)(qa + c4 * 4);
                float4 k4 = *(const float4*)(cb + c4 * 4);
                S += q4.x * k4.x + q4.y * k4.y + q4.z * k4.z + q4.w * k4.w;
            }
            const float* qr = qr_s + h * 32 + ch * 16;
            const float* kb = kr_s + jq * 36 + ch * 16;
            #pragma unroll
            for (int i4 = 0; i4 < 4; ++i4) {
                float4 q4 = *(const float4*)(qr + i4 * 4);
                float4 k4 = *(const float4*)(kb + i4 * 4);
                S += q4.x * k4.x + q4.y * k4.y + q4.z * k4.z + q4.w * k4.w;
            }
        }
        S += __shfl_xor(S, 32);

        float mx = S;
        #pragma unroll
        for (int off = 16; off > 0; off >>= 1) mx = fmaxf(mx, __shfl_xor(mx, off));
        float m_new = fmaxf(m_run, mx);
        float r = expf(m_run - m_new);
        float p = expf(S - m_new);
        float ps = p;
        #pragma unroll
        for (int off = 16; off > 0; off >>= 1) ps += __shfl_xor(ps, off);
        l_run = l_run * r + ps;
        m_run = m_new;
        acc.x *= r; acc.y *= r; acc.z *= r; acc.w *= r;

        {
            const float* cb = ckv_s + l * 4;
            #pragma unroll 8
            for (int j = 0; j < 32; ++j) {
                float pj = __shfl(p, j);
                float4 v4 = *(const float4*)(cb + j * 260);
                acc.x += pj * v4.x; acc.y += pj * v4.y;
                acc.z += pj * v4.z; acc.w += pj * v4.w;
            }
        }
        __syncthreads();
    }

    float inv = 1.f / l_run;
    float4 o = make_float4(acc.x * inv, acc.y * inv, acc.z * inv, acc.w * inv);
    *(float4*)(olat + (long)t * 2048 + h * 256 + l * 4) = o;
}

extern "C" void kernel_launch(void* const* d_in, const int* in_sizes, int n_in,
                              void* d_out, int out_size, void* d_ws, size_t ws_size,
                              hipStream_t stream)
{
    const float* x         = (const float*)d_in[0];
    const float* w_q_idx   = (const float*)d_in[1];
    const float* w_k_idx   = (const float*)d_in[2];
    const float* w_idx     = (const float*)d_in[3];
    const float* raw_delta = (const float*)d_in[4];
    const float* w_dkv     = (const float*)d_in[5];
    const float* w_uk      = (const float*)d_in[6];
    const float* w_uv      = (const float*)d_in[7];
    const float* w_dq      = (const float*)d_in[8];
    const float* w_uq      = (const float*)d_in[9];
    const float* w_qr      = (const float*)d_in[10];
    const float* w_kr      = (const float*)d_in[11];
    const float* w_out     = (const float*)d_in[12];
    (void)in_sizes; (void)n_in; (void)out_size; (void)ws_size;
    float* out = (float*)d_out;

    float* ws = (float*)d_ws;
    float* qI    = ws;        ws += 1024 * 512;
    float* kI    = ws;        ws += 1024 * 64;
    float* ckv   = ws;        ws += 1024 * 256;
    float* cq    = ws;        ws += 1024 * 512;
    float* xkr   = ws;        ws += 1024 * 32;
    float* qrp   = ws;        ws += 1024 * 256;
    float* qrr   = ws;        ws += 1024 * 256;
    float* qc    = ws;        ws += 1024 * 512;
    float* qabs  = ws;        ws += 1024 * 2048;
    float* Ibuf  = ws;        ws += 1024 * 1024;
    int*   idxb  = (int*)ws;  ws += 1024 * 128;
    float* olat  = ws;        ws += 1024 * 2048;
    float* outh  = ws;        ws += 1024 * 512;
    float* mu    = ws;        ws += 1024 * 32;
    float* cscb  = ws;        ws += 128 * 16;
    float* cssb  = ws;        ws += 128 * 16;
    float* wukT  = ws;        ws += 512 * 256;
    float* part  = ws;        ws += 2097152;   // split-K partials (reused)

    // ---- stage 1: five x-projections. qI/kI KS=1 (selection, bitwise);
    //      ckv/cq/xkr KS=2 (value path).
    {
        MGK m{};
        for (int i = 0; i < 5; ++i) { m.A[i] = x; m.lda[i] = 1024; m.K[i] = 1024; }
        float* ckvP = part;                 // 2 x 262144
        float* cqP  = part + 524288;        // 2 x 524288
        float* xkrP = part + 1572864;       // 2 x 32768
        m.B[0]=w_q_idx; m.Cw[0]=qI;   m.ldb[0]=512; m.wldc[0]=512; m.N[0]=512; m.KS[0]=1; m.ntiles[0]=8; m.pstride[0]=0;
        m.B[1]=w_k_idx; m.Cw[1]=kI;   m.ldb[1]=64;  m.wldc[1]=64;  m.N[1]=64;  m.KS[1]=1; m.ntiles[1]=1; m.pstride[1]=0;
        m.B[2]=w_dkv;   m.Cw[2]=ckvP; m.ldb[2]=256; m.wldc[2]=256; m.N[2]=256; m.KS[2]=2; m.ntiles[2]=4; m.pstride[2]=262144;
        m.B[3]=w_dq;    m.Cw[3]=cqP;  m.ldb[3]=512; m.wldc[3]=512; m.N[3]=512; m.KS[3]=2; m.ntiles[3]=8; m.pstride[3]=524288;
        m.B[4]=w_kr;    m.Cw[4]=xkrP; m.ldb[4]=32;  m.wldc[4]=32;  m.N[4]=32;  m.KS[4]=2; m.ntiles[4]=1; m.pstride[4]=32768;
        int us[6] = {0, 8, 9, 17, 33, 35};
        for (int i = 0; i < 6; ++i) m.ustart[i] = us[i];
        m.ne = 5;
        gemmk<<<dim3(35, 64), dim3(128), 0, stream>>>(m);

        RED8 r{};
        r.src[0]=(const float4*)ckvP; r.dst[0]=(float4*)ckv; r.slab[0]=65536;  r.ks[0]=2; r.cshift[0]=6; r.lddst[0]=64;
        r.src[1]=(const float4*)cqP;  r.dst[1]=(float4*)cq;  r.slab[1]=131072; r.ks[1]=2; r.cshift[1]=7; r.lddst[1]=128;
        r.src[2]=(const float4*)xkrP; r.dst[2]=(float4*)xkr; r.slab[2]=8192;   r.ks[2]=2; r.cshift[2]=3; r.lddst[2]=8;
        r.bstart[0]=0; r.bstart[1]=256; r.bstart[2]=768; r.bstart[3]=800;
        r.ne = 3;
        reduce_k<<<dim3(800), dim3(256), 0, stream>>>(r);
    }

    prep_kernel<<<dim3(648), dim3(256), 0, stream>>>(xkr, raw_delta, w_uk, mu, cscb, cssb, wukT);

    // ---- stage 2: qc, qrp (value path, KS=2)
    {
        MGK m{};
        for (int i = 0; i < 2; ++i) { m.A[i] = cq; m.lda[i] = 512; m.K[i] = 512; }
        float* qcP  = part;               // 2 x 524288
        float* qrpP = part + 1048576;     // 2 x 262144
        m.B[0]=w_uq; m.Cw[0]=qcP;  m.ldb[0]=512; m.wldc[0]=512; m.N[0]=512; m.KS[0]=2; m.ntiles[0]=8; m.pstride[0]=524288;
        m.B[1]=w_qr; m.Cw[1]=qrpP; m.ldb[1]=256; m.wldc[1]=256; m.N[1]=256; m.KS[1]=2; m.ntiles[1]=4; m.pstride[1]=262144;
        m.ustart[0]=0; m.ustart[1]=16; m.ustart[2]=24;
        m.ne = 2;
        gemmk<<<dim3(24, 64), dim3(128), 0, stream>>>(m);

        RED8 r{};
        r.src[0]=(const float4*)qcP;  r.dst[0]=(float4*)qc;  r.slab[0]=131072; r.ks[0]=2; r.cshift[0]=7; r.lddst[0]=128;
        r.src[1]=(const float4*)qrpP; r.dst[1]=(float4*)qrp; r.slab[1]=65536;  r.ks[1]=2; r.cshift[1]=6; r.lddst[1]=64;
        r.bstart[0]=0; r.bstart[1]=512; r.bstart[2]=768;
        r.ne = 2;
        reduce_k<<<dim3(768), dim3(256), 0, stream>>>(r);
    }

    pope_q_kernel<<<dim3(1024), dim3(128), 0, stream>>>(qrp, raw_delta, qrr);

    // ---- qabs as 8 GEMM entries: qabs[t][h*256+c] = qc_h[t,:] . w_ukT_h[:,c]
    {
        MGK m{};
        for (int h = 0; h < 8; ++h) {
            m.A[h] = qc + h * 64;          m.lda[h] = 512; m.K[h] = 64;
            m.B[h] = wukT + (h * 64) * 256; m.ldb[h] = 256;
            m.Cw[h] = qabs + h * 256;      m.wldc[h] = 2048; m.N[h] = 256;
            m.KS[h] = 1; m.ntiles[h] = 4; m.pstride[h] = 0;
            m.ustart[h] = h * 4;
        }
        m.ustart[8] = 32;
        m.ne = 8;
        gemmk<<<dim3(32, 64), dim3(128), 0, stream>>>(m);
    }

    // ---- indexer + exact top-k (bitwise-stable selection path)
    indexer_kernel<<<dim3(16, 32), dim3(256), 0, stream>>>(qI, kI, w_idx, Ibuf);
    topk_kernel<<<dim3(256), dim3(256), 0, stream>>>(Ibuf, idxb);

    // ---- fused attention -> latent output
    attn_kernel<<<dim3(1024), dim3(512), 0, stream>>>(qabs, qrr, ckv, mu, cscb, cssb, idxb, olat);

    // ---- stage 3: o_lat @ w_uv per head (KS=2, compact partials)
    {
        MGK m{};
        for (int h = 0; h < 8; ++h) {
            m.A[h] = olat + h * 256;  m.lda[h] = 2048; m.K[h] = 256;
            m.B[h] = w_uv + h * 64;   m.ldb[h] = 512;
            m.Cw[h] = part + h * 131072; m.wldc[h] = 64; m.N[h] = 64;
            m.KS[h] = 2; m.ntiles[h] = 1; m.pstride[h] = 65536;
            m.ustart[h] = h * 2;
        }
        m.ustart[8] = 16;
        m.ne = 8;
        gemmk<<<dim3(16, 64), dim3(128), 0, stream>>>(m);

        RED8 r{};
        for (int h = 0; h < 8; ++h) {
            r.src[h] = (const float4*)(part + h * 131072);
            r.dst[h] = (float4*)(outh) + h * 16;
            r.slab[h] = 16384; r.ks[h] = 2; r.cshift[h] = 4; r.lddst[h] = 128;
            r.bstart[h] = h * 64;
        }
        r.bstart[8] = 512;
        r.ne = 8;
        reduce_k<<<dim3(512), dim3(256), 0, stream>>>(r);
    }

    // ---- stage 4: outh @ w_out (KS=2)
    {
        MGK m{};
        m.A[0] = outh;  m.lda[0] = 512;  m.K[0] = 512;
        m.B[0] = w_out; m.ldb[0] = 1024;
        m.Cw[0] = part; m.wldc[0] = 1024; m.N[0] = 1024;
        m.KS[0] = 2; m.ntiles[0] = 16; m.pstride[0] = 1048576;
        m.ustart[0] = 0; m.ustart[1] = 32;
        m.ne = 1;
        gemmk<<<dim3(32, 64), dim3(128), 0, stream>>>(m);

        RED8 r{};
        r.src[0] = (const float4*)part; r.dst[0] = (float4*)out;
        r.slab[0] = 262144; r.ks[0] = 2; r.cshift[0] = 8; r.lddst[0] = 256;
        r.bstart[0] = 0; r.bstart[1] = 1024;
        r.ne = 1;
        reduce_k<<<dim3(1024), dim3(256), 0, stream>>>(r);
    }
}

// Round 6
// 257.013 us; speedup vs baseline: 3.0625x; 1.1769x over previous
//
#include <hip/hip_runtime.h>
#include <math.h>

#define S_LEN 1024
#define NH 8

typedef __attribute__((ext_vector_type(8))) short bf16x8;
typedef __attribute__((ext_vector_type(4))) float f32x4;

__device__ __forceinline__ float sp_softplus(float x) {
    return fmaxf(x, 0.f) + log1pf(expf(-fabsf(x)));
}

__device__ __forceinline__ unsigned short bfu(float f) {
    unsigned u = __float_as_uint(f);
    unsigned r = (u + 0x7FFFu + ((u >> 16) & 1u)) >> 16;   // RNE
    return (unsigned short)r;
}

// ============ fp32 routed GEMM w/ split-K (SELECTION PATH ONLY) ==============
struct MGK {
    const float* A[4]; const float* B[4]; float* Cw[4];
    int lda[4], ldb[4], wldc[4], K[4], N[4], KS[4], ntiles[4];
    long pstride[4];
    int ustart[5]; int ne;
};

__global__ __launch_bounds__(128) void gemmk(MGK mg)
{
    int u = blockIdx.x;
    int e = 0;
    #pragma unroll
    for (int i = 1; i < 4; ++i) if (i < mg.ne && u >= mg.ustart[i]) e = i;
    int local = u - mg.ustart[e];
    int nt = local % mg.ntiles[e];
    int ks = local / mg.ntiles[e];
    const float* A = mg.A[e];
    const float* B = mg.B[e];
    int lda = mg.lda[e], ldb = mg.ldb[e], ldc = mg.wldc[e];
    int N = mg.N[e];
    int kb = ks * (mg.K[e] / mg.KS[e]);
    int ke = kb + mg.K[e] / mg.KS[e];
    float* C = mg.Cw[e] + ks * mg.pstride[e];
    int m0 = blockIdx.y * 16, n0 = nt * 64;

    __shared__ float As[16][18];
    __shared__ float Bs[16][68];
    int t = threadIdx.x;
    int ar = t >> 2, ak = t & 3;
    int bk = t >> 3, bn = t & 7;
    int ty = t >> 4, tx = t & 15;
    bool ok0 = (n0 + bn * 4) < N;
    bool ok1 = (n0 + (bn + 8) * 4) < N;

    float4 aN = make_float4(0.f, 0.f, 0.f, 0.f);
    if (t < 64) aN = *(const float4*)(A + (long)(m0 + ar) * lda + kb + ak * 4);
    float4 b0 = ok0 ? *(const float4*)(B + (long)(kb + bk) * ldb + n0 + bn * 4)
                    : make_float4(0.f, 0.f, 0.f, 0.f);
    float4 b1 = ok1 ? *(const float4*)(B + (long)(kb + bk) * ldb + n0 + (bn + 8) * 4)
                    : make_float4(0.f, 0.f, 0.f, 0.f);
    float acc[2][4] = {};
    for (int k0 = kb; k0 < ke; k0 += 16) {
        if (t < 64) {
            As[ak * 4 + 0][ar] = aN.x;
            As[ak * 4 + 1][ar] = aN.y;
            As[ak * 4 + 2][ar] = aN.z;
            As[ak * 4 + 3][ar] = aN.w;
        }
        *(float4*)&Bs[bk][bn * 4] = b0;
        *(float4*)&Bs[bk][(bn + 8) * 4] = b1;
        __syncthreads();
        if (k0 + 16 < ke) {
            if (t < 64) aN = *(const float4*)(A + (long)(m0 + ar) * lda + (k0 + 16) + ak * 4);
            b0 = ok0 ? *(const float4*)(B + (long)(k0 + 16 + bk) * ldb + n0 + bn * 4)
                     : make_float4(0.f, 0.f, 0.f, 0.f);
            b1 = ok1 ? *(const float4*)(B + (long)(k0 + 16 + bk) * ldb + n0 + (bn + 8) * 4)
                     : make_float4(0.f, 0.f, 0.f, 0.f);
        }
        #pragma unroll
        for (int kk = 0; kk < 16; ++kk) {
            float2 a = *(float2*)&As[kk][ty * 2];
            float4 b = *(float4*)&Bs[kk][tx * 4];
            acc[0][0] += a.x * b.x; acc[0][1] += a.x * b.y;
            acc[0][2] += a.x * b.z; acc[0][3] += a.x * b.w;
            acc[1][0] += a.y * b.x; acc[1][1] += a.y * b.y;
            acc[1][2] += a.y * b.z; acc[1][3] += a.y * b.w;
        }
        __syncthreads();
    }
    if ((n0 + tx * 4) < N) {
        #pragma unroll
        for (int i = 0; i < 2; ++i) {
            float4 v = make_float4(acc[i][0], acc[i][1], acc[i][2], acc[i][3]);
            *(float4*)(C + (long)(m0 + ty * 2 + i) * ldc + n0 + tx * 4) = v;
        }
    }
}

// ---- deterministic split-K reduce ------------------------------------------
struct RED4 {
    const float4* src[4]; float4* dst[4];
    long slab[4]; int ks[4];
    int bstart[5]; int ne;
};
__global__ __launch_bounds__(256) void reduce_k(RED4 rd)
{
    int b = blockIdx.x;
    int e = 0;
    #pragma unroll
    for (int i = 1; i < 4; ++i) if (i < rd.ne && b >= rd.bstart[i]) e = i;
    long i = (long)(b - rd.bstart[e]) * 256 + threadIdx.x;
    const float4* s = rd.src[e];
    float4 a = s[i];
    for (int k = 1; k < rd.ks[e]; ++k) {
        float4 v = s[(long)k * rd.slab[e] + i];
        a.x += v.x; a.y += v.y; a.z += v.z; a.w += v.w;
    }
    rd.dst[e][i] = a;
}

// ============ bf16 MFMA routed multi-GEMM (VALUE PATH) =======================
// C[1024,N] = A[1024,K](fp32, cast on stage) @ B^T stored [N][K] bf16.
// 64x64 tile, 256 thr = 4 waves, each wave a 32x32 quadrant via 2x2 frags of
// v_mfma_f32_16x16x32_bf16. A/B lane layout: row/col = l&15, k = (l>>4)*8+j.
// C/D layout: col = l&15, row = (l>>4)*4 + reg  [m89-verified].
struct MFG {
    const float* A[10]; const unsigned short* B[10]; float* C[10];
    int lda[10], ldb[10], ldc[10], K[10], N[10];
    int tstart[11]; int ne;
};

__global__ __launch_bounds__(256) void mgemm(MFG mg)
{
    int bx = blockIdx.x, e = 0;
    #pragma unroll
    for (int i = 1; i < 10; ++i) if (i < mg.ne && bx >= mg.tstart[i]) e = i;
    const float* A = mg.A[e];
    const unsigned short* B = mg.B[e];
    float* C = mg.C[e];
    int lda = mg.lda[e], ldb = mg.ldb[e], ldc = mg.ldc[e];
    int K = mg.K[e], N = mg.N[e];
    int m0 = blockIdx.y * 64, n0 = (bx - mg.tstart[e]) * 64;

    __shared__ unsigned short As[64][40];   // stride 40 bf16 = 80B (bank spread)
    __shared__ unsigned short Bs[64][40];
    int t = threadIdx.x;
    int srow = t >> 2, skq = t & 3;         // staging: row, k-octet
    int wid = t >> 6, l = t & 63;
    int wm = (wid >> 1) * 32, wn = (wid & 1) * 32;
    int fr = l & 15, fk = (l >> 4) * 8;
    bool bok = (n0 + srow) < N;

    f32x4 acc00 = {0.f, 0.f, 0.f, 0.f};
    f32x4 acc01 = {0.f, 0.f, 0.f, 0.f};
    f32x4 acc10 = {0.f, 0.f, 0.f, 0.f};
    f32x4 acc11 = {0.f, 0.f, 0.f, 0.f};

    for (int k0 = 0; k0 < K; k0 += 32) {
        {   // stage A (fp32 -> bf16)
            const float* ap = A + (long)(m0 + srow) * lda + k0 + skq * 8;
            float4 v0 = *(const float4*)ap;
            float4 v1 = *(const float4*)(ap + 4);
            unsigned short* d = &As[srow][skq * 8];
            d[0] = bfu(v0.x); d[1] = bfu(v0.y); d[2] = bfu(v0.z); d[3] = bfu(v0.w);
            d[4] = bfu(v1.x); d[5] = bfu(v1.y); d[6] = bfu(v1.z); d[7] = bfu(v1.w);
        }
        {   // stage B (already bf16, [N][K] layout)
            uint4 bv = make_uint4(0u, 0u, 0u, 0u);
            if (bok) bv = *(const uint4*)(B + (long)(n0 + srow) * ldb + k0 + skq * 8);
            *(uint4*)&Bs[srow][skq * 8] = bv;
        }
        __syncthreads();
        bf16x8 a0 = *(bf16x8*)&As[wm + fr][fk];
        bf16x8 a1 = *(bf16x8*)&As[wm + 16 + fr][fk];
        bf16x8 b0 = *(bf16x8*)&Bs[wn + fr][fk];
        bf16x8 b1 = *(bf16x8*)&Bs[wn + 16 + fr][fk];
        acc00 = __builtin_amdgcn_mfma_f32_16x16x32_bf16(a0, b0, acc00, 0, 0, 0);
        acc01 = __builtin_amdgcn_mfma_f32_16x16x32_bf16(a0, b1, acc01, 0, 0, 0);
        acc10 = __builtin_amdgcn_mfma_f32_16x16x32_bf16(a1, b0, acc10, 0, 0, 0);
        acc11 = __builtin_amdgcn_mfma_f32_16x16x32_bf16(a1, b1, acc11, 0, 0, 0);
        __syncthreads();
    }
    int crow = (l >> 4) * 4;
    int col0 = n0 + wn + fr, col1 = n0 + wn + 16 + fr;
    if (col0 < N) {
        #pragma unroll
        for (int r = 0; r < 4; ++r) {
            C[(long)(m0 + wm + crow + r) * ldc + col0]      = acc00[r];
            C[(long)(m0 + wm + 16 + crow + r) * ldc + col0] = acc10[r];
        }
    }
    if (col1 < N) {
        #pragma unroll
        for (int r = 0; r < 4; ++r) {
            C[(long)(m0 + wm + crow + r) * ldc + col1]      = acc01[r];
            C[(long)(m0 + wm + 16 + crow + r) * ldc + col1] = acc11[r];
        }
    }
}

// ---- tiled transpose+cast: src fp32 [K][N] -> dst bf16 [N][K] ---------------
struct TC8 {
    const float* src[8]; unsigned short* dst[8];
    int N[8], Kld[8], Ntiles[8];
    int bstart[9]; int ne;
};
__global__ __launch_bounds__(256) void tcast(TC8 tc)
{
    int b = blockIdx.x, e = 0;
    #pragma unroll
    for (int i = 1; i < 8; ++i) if (i < tc.ne && b >= tc.bstart[i]) e = i;
    int lb = b - tc.bstart[e];
    int nt = lb % tc.Ntiles[e], kt = lb / tc.Ntiles[e];
    const float* src = tc.src[e];
    unsigned short* dst = tc.dst[e];
    int N = tc.N[e], Kld = tc.Kld[e];
    int k0 = kt * 64, n0 = nt * 64;
    __shared__ unsigned short tile[64][65];
    int t = threadIdx.x;
    int c = t & 63, r4 = t >> 6;
    #pragma unroll
    for (int it = 0; it < 16; ++it) {
        int r = it * 4 + r4;
        float v = (n0 + c < N) ? src[(long)(k0 + r) * N + n0 + c] : 0.f;
        tile[r][c] = bfu(v);
    }
    __syncthreads();
    int wq = t & 7;
    #pragma unroll
    for (int itw = 0; itw < 2; ++itw) {
        int wr = itw * 32 + (t >> 3);
        if (n0 + wr < N) {
            unsigned short v[8];
            #pragma unroll
            for (int j = 0; j < 8; ++j) v[j] = tile[wq * 8 + j][wr];
            *(uint4*)(dst + (long)(n0 + wr) * Kld + k0 + wq * 8) = *(uint4*)v;
        }
    }
}

// ---- small prep: mu = softplus(xkr); key-PoPE cos/sin; w_uk cast ------------
__global__ __launch_bounds__(256) void prep_small(
    const float* __restrict__ xkr, const float* __restrict__ raw_delta,
    const float* __restrict__ w_uk,
    float* __restrict__ mu, float* __restrict__ csc, float* __restrict__ css,
    unsigned short* __restrict__ wukb)
{
    int b = blockIdx.x, tid = threadIdx.x;
    if (b < 128) {
        int i = b * 256 + tid;
        mu[i] = sp_softplus(xkr[i]);
    } else if (b < 136) {
        int idx = (b - 128) * 256 + tid;
        int j = idx >> 4, i = idx & 15;
        float rd = raw_delta[i];
        float delta = -6.283185307179586f * (1.f / (1.f + expf(-rd)));
        float th = exp2f(-(float)i * 0.83048202372184f);
        float ang = (float)j * th + delta;
        float sv, cv;
        sincosf(ang, &sv, &cv);
        csc[idx] = cv;
        css[idx] = sv;
    } else {
        int idx = (b - 136) * 256 + tid;   // 131072 items
        wukb[idx] = bfu(w_uk[idx]);
    }
}

// ---------------- PoPE for queries (unchanged) --------------------------------
__global__ __launch_bounds__(128) void pope_q_kernel(
    const float* __restrict__ pre, const float* __restrict__ raw_delta,
    float* __restrict__ outq)
{
    int t = blockIdx.x, tid = threadIdx.x;
    int h = tid >> 4, i = tid & 15;
    float rd = raw_delta[i];
    float delta = -6.283185307179586f * (1.f / (1.f + expf(-rd)));
    float th = exp2f(-(float)i * 0.83048202372184f);
    float ang = (float)t * th + delta;
    float sv, cv;
    sincosf(ang, &sv, &cv);
    float m1 = sp_softplus(pre[t * 256 + h * 32 + i]);
    float m2 = sp_softplus(pre[t * 256 + h * 32 + 16 + i]);
    outq[t * 256 + h * 32 + i]      = m1 * cv - m2 * sv;
    outq[t * 256 + h * 32 + 16 + i] = m1 * sv + m2 * cv;
}

// -------- lightning indexer (unchanged, fp32 selection path) ------------------
__global__ __launch_bounds__(256) void indexer_kernel(
    const float* __restrict__ qI, const float* __restrict__ kI,
    const float* __restrict__ w_idx, float* __restrict__ I)
{
    int sb = blockIdx.x, tb = blockIdx.y;
    if (sb * 64 > tb * 32 + 31) return;
    int t0 = tb * 32, s0 = sb * 64;
    __shared__ float ksT[64][68];
    __shared__ float qs[32][68];
    int t = threadIdx.x;
    {
        int r = t & 63, q = t >> 6;
        #pragma unroll
        for (int u = 0; u < 4; ++u) {
            int c4 = q * 4 + u;
            float4 v = *(const float4*)(kI + (long)(s0 + r) * 64 + c4 * 4);
            ksT[c4 * 4 + 0][r] = v.x;
            ksT[c4 * 4 + 1][r] = v.y;
            ksT[c4 * 4 + 2][r] = v.z;
            ksT[c4 * 4 + 3][r] = v.w;
        }
    }
    int ty = t >> 4, tx = t & 15;
    float accI[2][4] = {};
    for (int h = 0; h < 8; ++h) {
        __syncthreads();
        {
            int r = t >> 3, q = t & 7;
            *(float4*)&qs[r][q * 4] =
                *(const float4*)(qI + (long)(t0 + r) * 512 + h * 64 + q * 4);
            *(float4*)&qs[r][(q + 8) * 4] =
                *(const float4*)(qI + (long)(t0 + r) * 512 + h * 64 + (q + 8) * 4);
        }
        __syncthreads();
        float acc[2][4] = {};
        #pragma unroll
        for (int dc = 0; dc < 4; ++dc) {
            float a0[16], a1[16];
            #pragma unroll
            for (int u = 0; u < 4; ++u) {
                float4 v0 = *(float4*)&qs[ty * 2][dc * 16 + u * 4];
                float4 v1 = *(float4*)&qs[ty * 2 + 1][dc * 16 + u * 4];
                a0[u * 4 + 0] = v0.x; a0[u * 4 + 1] = v0.y; a0[u * 4 + 2] = v0.z; a0[u * 4 + 3] = v0.w;
                a1[u * 4 + 0] = v1.x; a1[u * 4 + 1] = v1.y; a1[u * 4 + 2] = v1.z; a1[u * 4 + 3] = v1.w;
            }
            #pragma unroll
            for (int kk = 0; kk < 16; ++kk) {
                int d = dc * 16 + kk;
                float4 b = *(float4*)&ksT[d][tx * 4];
                acc[0][0] += a0[kk] * b.x; acc[0][1] += a0[kk] * b.y;
                acc[0][2] += a0[kk] * b.z; acc[0][3] += a0[kk] * b.w;
                acc[1][0] += a1[kk] * b.x; acc[1][1] += a1[kk] * b.y;
                acc[1][2] += a1[kk] * b.z; acc[1][3] += a1[kk] * b.w;
            }
        }
        float wh = w_idx[h];
        #pragma unroll
        for (int i = 0; i < 2; ++i)
            #pragma unroll
            for (int j = 0; j < 4; ++j)
                accI[i][j] += wh * fmaxf(acc[i][j], 0.f);
    }
    #pragma unroll
    for (int i = 0; i < 2; ++i) {
        float4 v = make_float4(accI[i][0], accI[i][1], accI[i][2], accI[i][3]);
        *(float4*)&I[(long)(t0 + ty * 2 + i) * 1024 + s0 + tx * 4] = v;
    }
}

// -------- exact top-k (unchanged) ---------------------------------------------
__global__ __launch_bounds__(256) void topk_kernel(
    const float* __restrict__ I, int* __restrict__ idxout)
{
    int t = blockIdx.x * 4 + (threadIdx.x >> 6);
    int lane = threadIdx.x & 63;
    int smin = max(0, t - 63);
    int w = min(64, t + 1);
    if (lane < w) idxout[t * 128 + lane] = smin + lane;
    for (int q = t + 1 + lane; q < 128; q += 64)
        idxout[t * 128 + q] = q;
    int f = max(0, t - 63);
    int m = min(f, 64);
    if (m == 0) return;
    const float* row = I + (long)t * 1024;
    unsigned long long key[16];
    #pragma unroll
    for (int i = 0; i < 16; ++i) {
        int s = i * 64 + lane;
        key[i] = 0ull;
        if (s < f) {
            unsigned u = __float_as_uint(row[s]);
            unsigned ou = (u & 0x80000000u) ? ~u : (u | 0x80000000u);
            key[i] = ((unsigned long long)ou << 32) | (0xFFFFFFFFu - (unsigned)s);
        }
    }
    for (int it = 0; it < m; ++it) {
        unsigned long long best = key[0];
        #pragma unroll
        for (int i = 1; i < 16; ++i) best = key[i] > best ? key[i] : best;
        #pragma unroll
        for (int off = 32; off > 0; off >>= 1) {
            unsigned long long o = __shfl_xor(best, off, 64);
            best = o > best ? o : best;
        }
        int s = (int)(0xFFFFFFFFu - (unsigned)(best & 0xFFFFFFFFull));
        if (lane == 0) idxout[t * 128 + w + it] = s;
        if ((s & 63) == lane) {
            int slot = s >> 6;
            #pragma unroll
            for (int i = 0; i < 16; ++i)
                if (i == slot) key[i] = 0ull;
        }
    }
}

// -------- fused attention (unchanged from r4/r5) -------------------------------
__global__ __launch_bounds__(512) void attn_kernel(
    const float* __restrict__ qabs, const float* __restrict__ qrr,
    const float* __restrict__ ckv, const float* __restrict__ mu,
    const float* __restrict__ csc, const float* __restrict__ css,
    const int* __restrict__ idxb, float* __restrict__ olat)
{
    __shared__ float ckv_s[32 * 260];
    __shared__ float kr_s[32 * 36];
    __shared__ float qa_s[8 * 256];
    __shared__ float qr_s[8 * 32];
    __shared__ int   idx_s[128];

    int t = blockIdx.x, tid = threadIdx.x;
    int h = tid >> 6, l = tid & 63;
    const float scale = 0.10206207261596575f;

    if (tid < 128) idx_s[tid] = idxb[t * 128 + tid];
    {
        float4 v = ((const float4*)(qabs + (long)t * 2048))[tid];
        v.x *= scale; v.y *= scale; v.z *= scale; v.w *= scale;
        ((float4*)qa_s)[tid] = v;
    }
    if (tid < 64) {
        float4 v = ((const float4*)(qrr + (long)t * 256))[tid];
        v.x *= scale; v.y *= scale; v.z *= scale; v.w *= scale;
        ((float4*)qr_s)[tid] = v;
    }
    __syncthreads();

    float m_run = -INFINITY, l_run = 0.f;
    float4 acc = make_float4(0.f, 0.f, 0.f, 0.f);
    int jq = l & 31, ch = l >> 5;
    int sr = tid >> 4, sq = tid & 15;

    for (int chunk = 0; chunk < 4; ++chunk) {
        int j0 = chunk * 32;
        {
            int src = idx_s[j0 + sr];
            const float4* sp4 = (const float4*)(ckv + (long)src * 256);
            float4* dst = (float4*)(ckv_s + sr * 260);
            #pragma unroll
            for (int u = 0; u < 4; ++u) dst[sq * 4 + u] = sp4[sq * 4 + u];
        }
        {
            int src = idx_s[j0 + sr];
            float m1 = mu[src * 32 + sq];
            float m2 = mu[src * 32 + 16 + sq];
            float cv = csc[(j0 + sr) * 16 + sq];
            float sv = css[(j0 + sr) * 16 + sq];
            kr_s[sr * 36 + sq]      = m1 * cv - m2 * sv;
            kr_s[sr * 36 + 16 + sq] = m1 * sv + m2 * cv;
        }
        __syncthreads();

        float S = 0.f;
        {
            const float* qa = qa_s + h * 256 + ch * 128;
            const float* cb = ckv_s + jq * 260 + ch * 128;
            #pragma unroll 8
            for (int c4 = 0; c4 < 32; ++c4) {
                float4 q4 = *(const float4*)(qa + c4 * 4);
                float4 k4 = *(const float4*)(cb + c4 * 4);
                S += q4.x * k4.x + q4.y * k4.y + q4.z * k4.z + q4.w * k4.w;
            }
            const float* qr = qr_s + h * 32 + ch * 16;
            const float* kb = kr_s + jq * 36 + ch * 16;
            #pragma unroll
            for (int i4 = 0; i4 < 4; ++i4) {
                float4 q4 = *(const float4*)(qr + i4 * 4);
                float4 k4 = *(const float4*)(kb + i4 * 4);
                S += q4.x * k4.x + q4.y * k4.y + q4.z * k4.z + q4.w * k4.w;
            }
        }
        S += __shfl_xor(S, 32);

        float mx = S;
        #pragma unroll
        for (int off = 16; off > 0; off >>= 1) mx = fmaxf(mx, __shfl_xor(mx, off));
        float m_new = fmaxf(m_run, mx);
        float r = expf(m_run - m_new);
        float p = expf(S - m_new);
        float ps = p;
        #pragma unroll
        for (int off = 16; off > 0; off >>= 1) ps += __shfl_xor(ps, off);
        l_run = l_run * r + ps;
        m_run = m_new;
        acc.x *= r; acc.y *= r; acc.z *= r; acc.w *= r;

        {
            const float* cb = ckv_s + l * 4;
            #pragma unroll 8
            for (int j = 0; j < 32; ++j) {
                float pj = __shfl(p, j);
                float4 v4 = *(const float4*)(cb + j * 260);
                acc.x += pj * v4.x; acc.y += pj * v4.y;
                acc.z += pj * v4.z; acc.w += pj * v4.w;
            }
        }
        __syncthreads();
    }

    float inv = 1.f / l_run;
    float4 o = make_float4(acc.x * inv, acc.y * inv, acc.z * inv, acc.w * inv);
    *(float4*)(olat + (long)t * 2048 + h * 256 + l * 4) = o;
}

extern "C" void kernel_launch(void* const* d_in, const int* in_sizes, int n_in,
                              void* d_out, int out_size, void* d_ws, size_t ws_size,
                              hipStream_t stream)
{
    const float* x         = (const float*)d_in[0];
    const float* w_q_idx   = (const float*)d_in[1];
    const float* w_k_idx   = (const float*)d_in[2];
    const float* w_idx     = (const float*)d_in[3];
    const float* raw_delta = (const float*)d_in[4];
    const float* w_dkv     = (const float*)d_in[5];
    const float* w_uk      = (const float*)d_in[6];
    const float* w_uv      = (const float*)d_in[7];
    const float* w_dq      = (const float*)d_in[8];
    const float* w_uq      = (const float*)d_in[9];
    const float* w_qr      = (const float*)d_in[10];
    const float* w_kr      = (const float*)d_in[11];
    const float* w_out     = (const float*)d_in[12];
    (void)in_sizes; (void)n_in; (void)out_size; (void)ws_size;
    float* out = (float*)d_out;

    float* ws = (float*)d_ws;
    float* qI    = ws;        ws += 1024 * 512;
    float* kI    = ws;        ws += 1024 * 64;
    float* ckv   = ws;        ws += 1024 * 256;
    float* cq    = ws;        ws += 1024 * 512;
    float* xkr   = ws;        ws += 1024 * 32;
    float* qrp   = ws;        ws += 1024 * 256;
    float* qrr   = ws;        ws += 1024 * 256;
    float* qc    = ws;        ws += 1024 * 512;
    float* qabs  = ws;        ws += 1024 * 2048;
    float* Ibuf  = ws;        ws += 1024 * 1024;
    int*   idxb  = (int*)ws;  ws += 1024 * 128;
    float* olat  = ws;        ws += 1024 * 2048;
    float* outh  = ws;        ws += 1024 * 512;
    float* mu    = ws;        ws += 1024 * 32;
    float* cscb  = ws;        ws += 128 * 16;
    float* cssb  = ws;        ws += 128 * 16;
    unsigned short* wdkvT = (unsigned short*)ws;  ws += 131072;  // 256x1024 bf16
    unsigned short* wdqT  = (unsigned short*)ws;  ws += 262144;  // 512x1024
    unsigned short* wkrT  = (unsigned short*)ws;  ws += 16384;   // 32x1024
    unsigned short* wuqT  = (unsigned short*)ws;  ws += 131072;  // 512x512
    unsigned short* wqrT  = (unsigned short*)ws;  ws += 65536;   // 256x512
    unsigned short* wuvT  = (unsigned short*)ws;  ws += 65536;   // 512x256
    unsigned short* woutT = (unsigned short*)ws;  ws += 262144;  // 1024x512
    unsigned short* wukb  = (unsigned short*)ws;  ws += 65536;   // 256x512 (cast)
    float* part  = ws;        ws += 1310720;  // split-K partials (qI,kI)

    // ---- 1. selection-path GEMMs (fp32, split-K=2)
    {
        MGK m{};
        float* qIP = part;                 // 2 x 524288
        float* kIP = part + 1048576;       // 2 x 65536
        m.A[0]=x; m.lda[0]=1024; m.K[0]=1024;
        m.A[1]=x; m.lda[1]=1024; m.K[1]=1024;
        m.B[0]=w_q_idx; m.Cw[0]=qIP; m.ldb[0]=512; m.wldc[0]=512; m.N[0]=512; m.KS[0]=2; m.ntiles[0]=8; m.pstride[0]=524288;
        m.B[1]=w_k_idx; m.Cw[1]=kIP; m.ldb[1]=64;  m.wldc[1]=64;  m.N[1]=64;  m.KS[1]=2; m.ntiles[1]=1; m.pstride[1]=65536;
        m.ustart[0]=0; m.ustart[1]=16; m.ustart[2]=18;
        m.ne = 2;
        gemmk<<<dim3(18, 64), dim3(128), 0, stream>>>(m);
    }

    // ---- 2. weight transpose+cast to bf16 [N][K] (independent)
    {
        TC8 tc{};
        tc.src[0]=w_dkv; tc.dst[0]=wdkvT; tc.N[0]=256;  tc.Kld[0]=1024; tc.Ntiles[0]=4;
        tc.src[1]=w_dq;  tc.dst[1]=wdqT;  tc.N[1]=512;  tc.Kld[1]=1024; tc.Ntiles[1]=8;
        tc.src[2]=w_kr;  tc.dst[2]=wkrT;  tc.N[2]=32;   tc.Kld[2]=1024; tc.Ntiles[2]=1;
        tc.src[3]=w_uq;  tc.dst[3]=wuqT;  tc.N[3]=512;  tc.Kld[3]=512;  tc.Ntiles[3]=8;
        tc.src[4]=w_qr;  tc.dst[4]=wqrT;  tc.N[4]=256;  tc.Kld[4]=512;  tc.Ntiles[4]=4;
        tc.src[5]=w_uv;  tc.dst[5]=wuvT;  tc.N[5]=512;  tc.Kld[5]=256;  tc.Ntiles[5]=8;
        tc.src[6]=w_out; tc.dst[6]=woutT; tc.N[6]=1024; tc.Kld[6]=512;  tc.Ntiles[6]=16;
        // tiles: 64, 128, 16, 64, 32, 32, 128  -> starts:
        int bs[8] = {0, 64, 192, 208, 272, 304, 336, 464};
        for (int i = 0; i < 8; ++i) tc.bstart[i] = bs[i];
        tc.ne = 7;
        tcast<<<dim3(464), dim3(256), 0, stream>>>(tc);
    }

    // ---- 3. reduce split-K partials -> qI, kI
    {
        RED4 r{};
        r.src[0]=(const float4*)part;             r.dst[0]=(float4*)qI; r.slab[0]=131072; r.ks[0]=2;
        r.src[1]=(const float4*)(part + 1048576); r.dst[1]=(float4*)kI; r.slab[1]=16384;  r.ks[1]=2;
        r.bstart[0]=0; r.bstart[1]=512; r.bstart[2]=576;
        r.ne = 2;
        reduce_k<<<dim3(576), dim3(256), 0, stream>>>(r);
    }

    // ---- 4. stage-1 value projections (bf16 MFMA): ckv, cq, xkr
    {
        MFG m{};
        for (int i = 0; i < 3; ++i) { m.A[i]=x; m.lda[i]=1024; m.K[i]=1024; }
        m.B[0]=wdkvT; m.C[0]=ckv; m.ldb[0]=1024; m.ldc[0]=256; m.N[0]=256;
        m.B[1]=wdqT;  m.C[1]=cq;  m.ldb[1]=1024; m.ldc[1]=512; m.N[1]=512;
        m.B[2]=wkrT;  m.C[2]=xkr; m.ldb[2]=1024; m.ldc[2]=32;  m.N[2]=32;
        m.tstart[0]=0; m.tstart[1]=4; m.tstart[2]=12; m.tstart[3]=13;
        m.ne = 3;
        mgemm<<<dim3(13, 16), dim3(256), 0, stream>>>(m);
    }

    // ---- 5. small prep (mu/cos/sin need xkr; w_uk cast)
    prep_small<<<dim3(648), dim3(256), 0, stream>>>(xkr, raw_delta, w_uk, mu, cscb, cssb, wukb);

    // ---- 6. stage-2: qc, qrp (bf16 MFMA)
    {
        MFG m{};
        for (int i = 0; i < 2; ++i) { m.A[i]=cq; m.lda[i]=512; m.K[i]=512; }
        m.B[0]=wuqT; m.C[0]=qc;  m.ldb[0]=512; m.ldc[0]=512; m.N[0]=512;
        m.B[1]=wqrT; m.C[1]=qrp; m.ldb[1]=512; m.ldc[1]=256; m.N[1]=256;
        m.tstart[0]=0; m.tstart[1]=8; m.tstart[2]=12;
        m.ne = 2;
        mgemm<<<dim3(12, 16), dim3(256), 0, stream>>>(m);
    }

    pope_q_kernel<<<dim3(1024), dim3(128), 0, stream>>>(qrp, raw_delta, qrr);

    // ---- 7. qabs (bf16 MFMA, 8 head entries): B_h = wukb + h*64, ldb=512
    {
        MFG m{};
        for (int h = 0; h < 8; ++h) {
            m.A[h] = qc + h * 64;   m.lda[h] = 512;  m.K[h] = 64;
            m.B[h] = wukb + h * 64; m.ldb[h] = 512;
            m.C[h] = qabs + h * 256; m.ldc[h] = 2048; m.N[h] = 256;
            m.tstart[h] = h * 4;
        }
        m.tstart[8] = 32;
        m.ne = 8;
        mgemm<<<dim3(32, 16), dim3(256), 0, stream>>>(m);
    }

    // ---- 8. indexer + exact top-k (fp32 selection)
    indexer_kernel<<<dim3(16, 32), dim3(256), 0, stream>>>(qI, kI, w_idx, Ibuf);
    topk_kernel<<<dim3(256), dim3(256), 0, stream>>>(Ibuf, idxb);

    // ---- 9. fused attention -> olat
    attn_kernel<<<dim3(1024), dim3(512), 0, stream>>>(qabs, qrr, ckv, mu, cscb, cssb, idxb, olat);

    // ---- 10. stage-3: outh_h = olat_h @ w_uv_h (bf16 MFMA): B_h = wuvT + h*64*256
    {
        MFG m{};
        for (int h = 0; h < 8; ++h) {
            m.A[h] = olat + h * 256;      m.lda[h] = 2048; m.K[h] = 256;
            m.B[h] = wuvT + h * 64 * 256; m.ldb[h] = 256;
            m.C[h] = outh + h * 64;       m.ldc[h] = 512;  m.N[h] = 64;
            m.tstart[h] = h;
        }
        m.tstart[8] = 8;
        m.ne = 8;
        mgemm<<<dim3(8, 16), dim3(256), 0, stream>>>(m);
    }

    // ---- 11. stage-4: out = outh @ w_out (bf16 MFMA)
    {
        MFG m{};
        m.A[0] = outh;  m.lda[0] = 512; m.K[0] = 512;
        m.B[0] = woutT; m.ldb[0] = 512;
        m.C[0] = out;   m.ldc[0] = 1024; m.N[0] = 1024;
        m.tstart[0] = 0; m.tstart[1] = 16;
        m.ne = 1;
        mgemm<<<dim3(16, 16), dim3(256), 0, stream>>>(m);
    }
}

// Round 7
// 245.445 us; speedup vs baseline: 3.2069x; 1.0471x over previous
//
#include <hip/hip_runtime.h>
#include <math.h>

#define S_LEN 1024
#define NH 8

typedef __attribute__((ext_vector_type(8))) short bf16x8;
typedef __attribute__((ext_vector_type(4))) float f32x4;

__device__ __forceinline__ float sp_softplus(float x) {
    return fmaxf(x, 0.f) + log1pf(expf(-fabsf(x)));
}

__device__ __forceinline__ unsigned short bfu(float f) {
    unsigned u = __float_as_uint(f);
    unsigned r = (u + 0x7FFFu + ((u >> 16) & 1u)) >> 16;   // RNE
    return (unsigned short)r;
}

// ============ fp32 routed GEMM w/ split-K (SELECTION PATH ONLY) ==============
// Partials consumed directly by indexer (fused reduce).
struct MGK {
    const float* A[4]; const float* B[4]; float* Cw[4];
    int lda[4], ldb[4], wldc[4], K[4], N[4], KS[4], ntiles[4];
    long pstride[4];
    int ustart[5]; int ne;
};

__global__ __launch_bounds__(128) void gemmk(MGK mg)
{
    int u = blockIdx.x;
    int e = 0;
    #pragma unroll
    for (int i = 1; i < 4; ++i) if (i < mg.ne && u >= mg.ustart[i]) e = i;
    int local = u - mg.ustart[e];
    int nt = local % mg.ntiles[e];
    int ks = local / mg.ntiles[e];
    const float* A = mg.A[e];
    const float* B = mg.B[e];
    int lda = mg.lda[e], ldb = mg.ldb[e], ldc = mg.wldc[e];
    int N = mg.N[e];
    int kb = ks * (mg.K[e] / mg.KS[e]);
    int ke = kb + mg.K[e] / mg.KS[e];
    float* C = mg.Cw[e] + ks * mg.pstride[e];
    int m0 = blockIdx.y * 16, n0 = nt * 64;

    __shared__ float As[16][18];
    __shared__ float Bs[16][68];
    int t = threadIdx.x;
    int ar = t >> 2, ak = t & 3;
    int bk = t >> 3, bn = t & 7;
    int ty = t >> 4, tx = t & 15;
    bool ok0 = (n0 + bn * 4) < N;
    bool ok1 = (n0 + (bn + 8) * 4) < N;

    float4 aN = make_float4(0.f, 0.f, 0.f, 0.f);
    if (t < 64) aN = *(const float4*)(A + (long)(m0 + ar) * lda + kb + ak * 4);
    float4 b0 = ok0 ? *(const float4*)(B + (long)(kb + bk) * ldb + n0 + bn * 4)
                    : make_float4(0.f, 0.f, 0.f, 0.f);
    float4 b1 = ok1 ? *(const float4*)(B + (long)(kb + bk) * ldb + n0 + (bn + 8) * 4)
                    : make_float4(0.f, 0.f, 0.f, 0.f);
    float acc[2][4] = {};
    for (int k0 = kb; k0 < ke; k0 += 16) {
        if (t < 64) {
            As[ak * 4 + 0][ar] = aN.x;
            As[ak * 4 + 1][ar] = aN.y;
            As[ak * 4 + 2][ar] = aN.z;
            As[ak * 4 + 3][ar] = aN.w;
        }
        *(float4*)&Bs[bk][bn * 4] = b0;
        *(float4*)&Bs[bk][(bn + 8) * 4] = b1;
        __syncthreads();
        if (k0 + 16 < ke) {
            if (t < 64) aN = *(const float4*)(A + (long)(m0 + ar) * lda + (k0 + 16) + ak * 4);
            b0 = ok0 ? *(const float4*)(B + (long)(k0 + 16 + bk) * ldb + n0 + bn * 4)
                     : make_float4(0.f, 0.f, 0.f, 0.f);
            b1 = ok1 ? *(const float4*)(B + (long)(k0 + 16 + bk) * ldb + n0 + (bn + 8) * 4)
                     : make_float4(0.f, 0.f, 0.f, 0.f);
        }
        #pragma unroll
        for (int kk = 0; kk < 16; ++kk) {
            float2 a = *(float2*)&As[kk][ty * 2];
            float4 b = *(float4*)&Bs[kk][tx * 4];
            acc[0][0] += a.x * b.x; acc[0][1] += a.x * b.y;
            acc[0][2] += a.x * b.z; acc[0][3] += a.x * b.w;
            acc[1][0] += a.y * b.x; acc[1][1] += a.y * b.y;
            acc[1][2] += a.y * b.z; acc[1][3] += a.y * b.w;
        }
        __syncthreads();
    }
    if ((n0 + tx * 4) < N) {
        #pragma unroll
        for (int i = 0; i < 2; ++i) {
            float4 v = make_float4(acc[i][0], acc[i][1], acc[i][2], acc[i][3]);
            *(float4*)(C + (long)(m0 + ty * 2 + i) * ldc + n0 + tx * 4) = v;
        }
    }
}

// ============ bf16 MFMA routed multi-GEMM (VALUE PATH) =======================
struct MFG {
    const float* A[10]; const unsigned short* B[10]; float* C[10];
    int lda[10], ldb[10], ldc[10], K[10], N[10];
    int tstart[11]; int ne;
};

__global__ __launch_bounds__(256) void mgemm(MFG mg)
{
    int bx = blockIdx.x, e = 0;
    #pragma unroll
    for (int i = 1; i < 10; ++i) if (i < mg.ne && bx >= mg.tstart[i]) e = i;
    const float* A = mg.A[e];
    const unsigned short* B = mg.B[e];
    float* C = mg.C[e];
    int lda = mg.lda[e], ldb = mg.ldb[e], ldc = mg.ldc[e];
    int K = mg.K[e], N = mg.N[e];
    int m0 = blockIdx.y * 64, n0 = (bx - mg.tstart[e]) * 64;

    __shared__ unsigned short As[64][40];
    __shared__ unsigned short Bs[64][40];
    int t = threadIdx.x;
    int srow = t >> 2, skq = t & 3;
    int wid = t >> 6, l = t & 63;
    int wm = (wid >> 1) * 32, wn = (wid & 1) * 32;
    int fr = l & 15, fk = (l >> 4) * 8;
    bool bok = (n0 + srow) < N;

    f32x4 acc00 = {0.f, 0.f, 0.f, 0.f};
    f32x4 acc01 = {0.f, 0.f, 0.f, 0.f};
    f32x4 acc10 = {0.f, 0.f, 0.f, 0.f};
    f32x4 acc11 = {0.f, 0.f, 0.f, 0.f};

    for (int k0 = 0; k0 < K; k0 += 32) {
        {
            const float* ap = A + (long)(m0 + srow) * lda + k0 + skq * 8;
            float4 v0 = *(const float4*)ap;
            float4 v1 = *(const float4*)(ap + 4);
            unsigned short* d = &As[srow][skq * 8];
            d[0] = bfu(v0.x); d[1] = bfu(v0.y); d[2] = bfu(v0.z); d[3] = bfu(v0.w);
            d[4] = bfu(v1.x); d[5] = bfu(v1.y); d[6] = bfu(v1.z); d[7] = bfu(v1.w);
        }
        {
            uint4 bv = make_uint4(0u, 0u, 0u, 0u);
            if (bok) bv = *(const uint4*)(B + (long)(n0 + srow) * ldb + k0 + skq * 8);
            *(uint4*)&Bs[srow][skq * 8] = bv;
        }
        __syncthreads();
        bf16x8 a0 = *(bf16x8*)&As[wm + fr][fk];
        bf16x8 a1 = *(bf16x8*)&As[wm + 16 + fr][fk];
        bf16x8 b0 = *(bf16x8*)&Bs[wn + fr][fk];
        bf16x8 b1 = *(bf16x8*)&Bs[wn + 16 + fr][fk];
        acc00 = __builtin_amdgcn_mfma_f32_16x16x32_bf16(a0, b0, acc00, 0, 0, 0);
        acc01 = __builtin_amdgcn_mfma_f32_16x16x32_bf16(a0, b1, acc01, 0, 0, 0);
        acc10 = __builtin_amdgcn_mfma_f32_16x16x32_bf16(a1, b0, acc10, 0, 0, 0);
        acc11 = __builtin_amdgcn_mfma_f32_16x16x32_bf16(a1, b1, acc11, 0, 0, 0);
        __syncthreads();
    }
    int crow = (l >> 4) * 4;
    int col0 = n0 + wn + fr, col1 = n0 + wn + 16 + fr;
    if (col0 < N) {
        #pragma unroll
        for (int r = 0; r < 4; ++r) {
            C[(long)(m0 + wm + crow + r) * ldc + col0]      = acc00[r];
            C[(long)(m0 + wm + 16 + crow + r) * ldc + col0] = acc10[r];
        }
    }
    if (col1 < N) {
        #pragma unroll
        for (int r = 0; r < 4; ++r) {
            C[(long)(m0 + wm + crow + r) * ldc + col1]      = acc01[r];
            C[(long)(m0 + wm + 16 + crow + r) * ldc + col1] = acc11[r];
        }
    }
}

// ---- tiled transpose+cast: src fp32 [K][N] -> dst bf16 [N][K] ---------------
struct TC8 {
    const float* src[8]; unsigned short* dst[8];
    int N[8], Kld[8], Ntiles[8];
    int bstart[9]; int ne;
};
__global__ __launch_bounds__(256) void tcast(TC8 tc)
{
    int b = blockIdx.x, e = 0;
    #pragma unroll
    for (int i = 1; i < 8; ++i) if (i < tc.ne && b >= tc.bstart[i]) e = i;
    int lb = b - tc.bstart[e];
    int nt = lb % tc.Ntiles[e], kt = lb / tc.Ntiles[e];
    const float* src = tc.src[e];
    unsigned short* dst = tc.dst[e];
    int N = tc.N[e], Kld = tc.Kld[e];
    int k0 = kt * 64, n0 = nt * 64;
    __shared__ unsigned short tile[64][65];
    int t = threadIdx.x;
    int c = t & 63, r4 = t >> 6;
    #pragma unroll
    for (int it = 0; it < 16; ++it) {
        int r = it * 4 + r4;
        float v = (n0 + c < N) ? src[(long)(k0 + r) * N + n0 + c] : 0.f;
        tile[r][c] = bfu(v);
    }
    __syncthreads();
    int wq = t & 7;
    #pragma unroll
    for (int itw = 0; itw < 2; ++itw) {
        int wr = itw * 32 + (t >> 3);
        if (n0 + wr < N) {
            unsigned short v[8];
            #pragma unroll
            for (int j = 0; j < 8; ++j) v[j] = tile[wq * 8 + j][wr];
            *(uint4*)(dst + (long)(n0 + wr) * Kld + k0 + wq * 8) = *(uint4*)v;
        }
    }
}

// ---- small prep: mu = softplus(xkr); key-PoPE cos/sin; w_uk cast ------------
__global__ __launch_bounds__(256) void prep_small(
    const float* __restrict__ xkr, const float* __restrict__ raw_delta,
    const float* __restrict__ w_uk,
    float* __restrict__ mu, float* __restrict__ csc, float* __restrict__ css,
    unsigned short* __restrict__ wukb)
{
    int b = blockIdx.x, tid = threadIdx.x;
    if (b < 128) {
        int i = b * 256 + tid;
        mu[i] = sp_softplus(xkr[i]);
    } else if (b < 136) {
        int idx = (b - 128) * 256 + tid;
        int j = idx >> 4, i = idx & 15;
        float rd = raw_delta[i];
        float delta = -6.283185307179586f * (1.f / (1.f + expf(-rd)));
        float th = exp2f(-(float)i * 0.83048202372184f);
        float ang = (float)j * th + delta;
        float sv, cv;
        sincosf(ang, &sv, &cv);
        csc[idx] = cv;
        css[idx] = sv;
    } else {
        int idx = (b - 136) * 256 + tid;
        wukb[idx] = bfu(w_uk[idx]);
    }
}

// ---------------- PoPE for queries (unchanged) --------------------------------
__global__ __launch_bounds__(128) void pope_q_kernel(
    const float* __restrict__ pre, const float* __restrict__ raw_delta,
    float* __restrict__ outq)
{
    int t = blockIdx.x, tid = threadIdx.x;
    int h = tid >> 4, i = tid & 15;
    float rd = raw_delta[i];
    float delta = -6.283185307179586f * (1.f / (1.f + expf(-rd)));
    float th = exp2f(-(float)i * 0.83048202372184f);
    float ang = (float)t * th + delta;
    float sv, cv;
    sincosf(ang, &sv, &cv);
    float m1 = sp_softplus(pre[t * 256 + h * 32 + i]);
    float m2 = sp_softplus(pre[t * 256 + h * 32 + 16 + i]);
    outq[t * 256 + h * 32 + i]      = m1 * cv - m2 * sv;
    outq[t * 256 + h * 32 + 16 + i] = m1 * sv + m2 * cv;
}

// -------- lightning indexer w/ FUSED split-K reduce of qI/kI partials --------
// qIP: 2 slabs (stride 524288) of 1024x512; kIP: 2 slabs (stride 65536) of
// 1024x64. Staging sums slabs ks-ascending — bitwise identical to the old
// reduce_k pass, so Ibuf / top-k stay bit-identical (absmax canary).
__global__ __launch_bounds__(256) void indexer_kernel(
    const float* __restrict__ qIP, const float* __restrict__ kIP,
    const float* __restrict__ w_idx, float* __restrict__ I)
{
    int sb = blockIdx.x, tb = blockIdx.y;
    if (sb * 64 > tb * 32 + 31) return;
    int t0 = tb * 32, s0 = sb * 64;
    __shared__ float ksT[64][68];
    __shared__ float qs[32][68];
    int t = threadIdx.x;
    {
        int r = t & 63, q = t >> 6;
        #pragma unroll
        for (int u = 0; u < 4; ++u) {
            int c4 = q * 4 + u;
            float4 v  = *(const float4*)(kIP + (long)(s0 + r) * 64 + c4 * 4);
            float4 v2 = *(const float4*)(kIP + 65536 + (long)(s0 + r) * 64 + c4 * 4);
            v.x += v2.x; v.y += v2.y; v.z += v2.z; v.w += v2.w;
            ksT[c4 * 4 + 0][r] = v.x;
            ksT[c4 * 4 + 1][r] = v.y;
            ksT[c4 * 4 + 2][r] = v.z;
            ksT[c4 * 4 + 3][r] = v.w;
        }
    }
    int ty = t >> 4, tx = t & 15;
    float accI[2][4] = {};
    for (int h = 0; h < 8; ++h) {
        __syncthreads();
        {
            int r = t >> 3, q = t & 7;
            long base = (long)(t0 + r) * 512 + h * 64;
            float4 a0 = *(const float4*)(qIP + base + q * 4);
            float4 a1 = *(const float4*)(qIP + 524288 + base + q * 4);
            a0.x += a1.x; a0.y += a1.y; a0.z += a1.z; a0.w += a1.w;
            *(float4*)&qs[r][q * 4] = a0;
            float4 b0 = *(const float4*)(qIP + base + (q + 8) * 4);
            float4 b1 = *(const float4*)(qIP + 524288 + base + (q + 8) * 4);
            b0.x += b1.x; b0.y += b1.y; b0.z += b1.z; b0.w += b1.w;
            *(float4*)&qs[r][(q + 8) * 4] = b0;
        }
        __syncthreads();
        float acc[2][4] = {};
        #pragma unroll
        for (int dc = 0; dc < 4; ++dc) {
            float a0[16], a1[16];
            #pragma unroll
            for (int u = 0; u < 4; ++u) {
                float4 v0 = *(float4*)&qs[ty * 2][dc * 16 + u * 4];
                float4 v1 = *(float4*)&qs[ty * 2 + 1][dc * 16 + u * 4];
                a0[u * 4 + 0] = v0.x; a0[u * 4 + 1] = v0.y; a0[u * 4 + 2] = v0.z; a0[u * 4 + 3] = v0.w;
                a1[u * 4 + 0] = v1.x; a1[u * 4 + 1] = v1.y; a1[u * 4 + 2] = v1.z; a1[u * 4 + 3] = v1.w;
            }
            #pragma unroll
            for (int kk = 0; kk < 16; ++kk) {
                int d = dc * 16 + kk;
                float4 b = *(float4*)&ksT[d][tx * 4];
                acc[0][0] += a0[kk] * b.x; acc[0][1] += a0[kk] * b.y;
                acc[0][2] += a0[kk] * b.z; acc[0][3] += a0[kk] * b.w;
                acc[1][0] += a1[kk] * b.x; acc[1][1] += a1[kk] * b.y;
                acc[1][2] += a1[kk] * b.z; acc[1][3] += a1[kk] * b.w;
            }
        }
        float wh = w_idx[h];
        #pragma unroll
        for (int i = 0; i < 2; ++i)
            #pragma unroll
            for (int j = 0; j < 4; ++j)
                accI[i][j] += wh * fmaxf(acc[i][j], 0.f);
    }
    #pragma unroll
    for (int i = 0; i < 2; ++i) {
        float4 v = make_float4(accI[i][0], accI[i][1], accI[i][2], accI[i][3]);
        *(float4*)&I[(long)(t0 + ty * 2 + i) * 1024 + s0 + tx * 4] = v;
    }
}

// -------- exact top-k (unchanged) ---------------------------------------------
__global__ __launch_bounds__(256) void topk_kernel(
    const float* __restrict__ I, int* __restrict__ idxout)
{
    int t = blockIdx.x * 4 + (threadIdx.x >> 6);
    int lane = threadIdx.x & 63;
    int smin = max(0, t - 63);
    int w = min(64, t + 1);
    if (lane < w) idxout[t * 128 + lane] = smin + lane;
    for (int q = t + 1 + lane; q < 128; q += 64)
        idxout[t * 128 + q] = q;
    int f = max(0, t - 63);
    int m = min(f, 64);
    if (m == 0) return;
    const float* row = I + (long)t * 1024;
    unsigned long long key[16];
    #pragma unroll
    for (int i = 0; i < 16; ++i) {
        int s = i * 64 + lane;
        key[i] = 0ull;
        if (s < f) {
            unsigned u = __float_as_uint(row[s]);
            unsigned ou = (u & 0x80000000u) ? ~u : (u | 0x80000000u);
            key[i] = ((unsigned long long)ou << 32) | (0xFFFFFFFFu - (unsigned)s);
        }
    }
    for (int it = 0; it < m; ++it) {
        unsigned long long best = key[0];
        #pragma unroll
        for (int i = 1; i < 16; ++i) best = key[i] > best ? key[i] : best;
        #pragma unroll
        for (int off = 32; off > 0; off >>= 1) {
            unsigned long long o = __shfl_xor(best, off, 64);
            best = o > best ? o : best;
        }
        int s = (int)(0xFFFFFFFFu - (unsigned)(best & 0xFFFFFFFFull));
        if (lane == 0) idxout[t * 128 + w + it] = s;
        if ((s & 63) == lane) {
            int slot = s >> 6;
            #pragma unroll
            for (int i = 0; i < 16; ++i)
                if (i == slot) key[i] = 0ull;
        }
    }
}

// -------- fused attention v4: T14 async-stage (reg prefetch next chunk) -------
// block per query t, 512 threads (wave = head). Gather latency for chunk c+1
// hides under chunk c's QK/softmax/PV compute.
__global__ __launch_bounds__(512) void attn_kernel(
    const float* __restrict__ qabs, const float* __restrict__ qrr,
    const float* __restrict__ ckv, const float* __restrict__ mu,
    const float* __restrict__ csc, const float* __restrict__ css,
    const int* __restrict__ idxb, float* __restrict__ olat)
{
    __shared__ float ckv_s[32 * 260];
    __shared__ float kr_s[32 * 36];
    __shared__ float qa_s[8 * 256];
    __shared__ float qr_s[8 * 32];
    __shared__ int   idx_s[128];

    int t = blockIdx.x, tid = threadIdx.x;
    int h = tid >> 6, l = tid & 63;
    const float scale = 0.10206207261596575f;

    if (tid < 128) idx_s[tid] = idxb[t * 128 + tid];
    {
        float4 v = ((const float4*)(qabs + (long)t * 2048))[tid];
        v.x *= scale; v.y *= scale; v.z *= scale; v.w *= scale;
        ((float4*)qa_s)[tid] = v;
    }
    if (tid < 64) {
        float4 v = ((const float4*)(qrr + (long)t * 256))[tid];
        v.x *= scale; v.y *= scale; v.z *= scale; v.w *= scale;
        ((float4*)qr_s)[tid] = v;
    }
    __syncthreads();

    int sr = tid >> 4, sq = tid & 15;
    float4 pc0, pc1, pc2, pc3;
    float pm1, pm2, pcv, psv;
#define PREF(J0) { \
        int src_ = idx_s[(J0) + sr]; \
        const float4* sp4_ = (const float4*)(ckv + (long)src_ * 256); \
        pc0 = sp4_[sq * 4 + 0]; pc1 = sp4_[sq * 4 + 1]; \
        pc2 = sp4_[sq * 4 + 2]; pc3 = sp4_[sq * 4 + 3]; \
        pm1 = mu[src_ * 32 + sq]; pm2 = mu[src_ * 32 + 16 + sq]; \
        pcv = csc[((J0) + sr) * 16 + sq]; psv = css[((J0) + sr) * 16 + sq]; }
    PREF(0);

    float m_run = -INFINITY, l_run = 0.f;
    float4 acc = make_float4(0.f, 0.f, 0.f, 0.f);
    int jq = l & 31, ch = l >> 5;

    #pragma unroll
    for (int chunk = 0; chunk < 4; ++chunk) {
        __syncthreads();   // previous compute done reading LDS
        {   // write staged regs -> LDS
            float4* dst = (float4*)(ckv_s + sr * 260);
            dst[sq * 4 + 0] = pc0; dst[sq * 4 + 1] = pc1;
            dst[sq * 4 + 2] = pc2; dst[sq * 4 + 3] = pc3;
            kr_s[sr * 36 + sq]      = pm1 * pcv - pm2 * psv;
            kr_s[sr * 36 + 16 + sq] = pm1 * psv + pm2 * pcv;
        }
        if (chunk < 3) PREF((chunk + 1) * 32);   // issue next gather early (T14)
        __syncthreads();

        float S = 0.f;
        {
            const float* qa = qa_s + h * 256 + ch * 128;
            const float* cb = ckv_s + jq * 260 + ch * 128;
            #pragma unroll 8
            for (int c4 = 0; c4 < 32; ++c4) {
                float4 q4 = *(const float4*)(qa + c4 * 4);
                float4 k4 = *(const float4*)(cb + c4 * 4);
                S += q4.x * k4.x + q4.y * k4.y + q4.z * k4.z + q4.w * k4.w;
            }
            const float* qr = qr_s + h * 32 + ch * 16;
            const float* kb = kr_s + jq * 36 + ch * 16;
            #pragma unroll
            for (int i4 = 0; i4 < 4; ++i4) {
                float4 q4 = *(const float4*)(qr + i4 * 4);
                float4 k4 = *(const float4*)(kb + i4 * 4);
                S += q4.x * k4.x + q4.y * k4.y + q4.z * k4.z + q4.w * k4.w;
            }
        }
        S += __shfl_xor(S, 32);

        float mx = S;
        #pragma unroll
        for (int off = 16; off > 0; off >>= 1) mx = fmaxf(mx, __shfl_xor(mx, off));
        float m_new = fmaxf(m_run, mx);
        float r = expf(m_run - m_new);
        float p = expf(S - m_new);
        float ps = p;
        #pragma unroll
        for (int off = 16; off > 0; off >>= 1) ps += __shfl_xor(ps, off);
        l_run = l_run * r + ps;
        m_run = m_new;
        acc.x *= r; acc.y *= r; acc.z *= r; acc.w *= r;

        {
            const float* cb = ckv_s + l * 4;
            #pragma unroll 8
            for (int j = 0; j < 32; ++j) {
                float pj = __shfl(p, j);
                float4 v4 = *(const float4*)(cb + j * 260);
                acc.x += pj * v4.x; acc.y += pj * v4.y;
                acc.z += pj * v4.z; acc.w += pj * v4.w;
            }
        }
    }
#undef PREF

    float inv = 1.f / l_run;
    float4 o = make_float4(acc.x * inv, acc.y * inv, acc.z * inv, acc.w * inv);
    *(float4*)(olat + (long)t * 2048 + h * 256 + l * 4) = o;
}

extern "C" void kernel_launch(void* const* d_in, const int* in_sizes, int n_in,
                              void* d_out, int out_size, void* d_ws, size_t ws_size,
                              hipStream_t stream)
{
    const float* x         = (const float*)d_in[0];
    const float* w_q_idx   = (const float*)d_in[1];
    const float* w_k_idx   = (const float*)d_in[2];
    const float* w_idx     = (const float*)d_in[3];
    const float* raw_delta = (const float*)d_in[4];
    const float* w_dkv     = (const float*)d_in[5];
    const float* w_uk      = (const float*)d_in[6];
    const float* w_uv      = (const float*)d_in[7];
    const float* w_dq      = (const float*)d_in[8];
    const float* w_uq      = (const float*)d_in[9];
    const float* w_qr      = (const float*)d_in[10];
    const float* w_kr      = (const float*)d_in[11];
    const float* w_out     = (const float*)d_in[12];
    (void)in_sizes; (void)n_in; (void)out_size; (void)ws_size;
    float* out = (float*)d_out;

    float* ws = (float*)d_ws;
    float* ckv   = ws;        ws += 1024 * 256;
    float* cq    = ws;        ws += 1024 * 512;
    float* xkr   = ws;        ws += 1024 * 32;
    float* qrp   = ws;        ws += 1024 * 256;
    float* qrr   = ws;        ws += 1024 * 256;
    float* qc    = ws;        ws += 1024 * 512;
    float* qabs  = ws;        ws += 1024 * 2048;
    float* Ibuf  = ws;        ws += 1024 * 1024;
    int*   idxb  = (int*)ws;  ws += 1024 * 128;
    float* olat  = ws;        ws += 1024 * 2048;
    float* outh  = ws;        ws += 1024 * 512;
    float* mu    = ws;        ws += 1024 * 32;
    float* cscb  = ws;        ws += 128 * 16;
    float* cssb  = ws;        ws += 128 * 16;
    unsigned short* wdkvT = (unsigned short*)ws;  ws += 131072;  // 256x1024 bf16
    unsigned short* wdqT  = (unsigned short*)ws;  ws += 262144;  // 512x1024
    unsigned short* wkrT  = (unsigned short*)ws;  ws += 16384;   // 32x1024
    unsigned short* wuqT  = (unsigned short*)ws;  ws += 131072;  // 512x512
    unsigned short* wqrT  = (unsigned short*)ws;  ws += 65536;   // 256x512
    unsigned short* wuvT  = (unsigned short*)ws;  ws += 65536;   // 512x256
    unsigned short* woutT = (unsigned short*)ws;  ws += 262144;  // 1024x512
    unsigned short* wukb  = (unsigned short*)ws;  ws += 65536;   // 256x512 (cast)
    float* part  = ws;        ws += 1310720;  // qI/kI split-K partials

    // ---- 1. selection-path GEMMs (fp32, split-K=2, partials only)
    {
        MGK m{};
        float* qIP = part;                 // 2 x 524288
        float* kIP = part + 1048576;       // 2 x 65536
        m.A[0]=x; m.lda[0]=1024; m.K[0]=1024;
        m.A[1]=x; m.lda[1]=1024; m.K[1]=1024;
        m.B[0]=w_q_idx; m.Cw[0]=qIP; m.ldb[0]=512; m.wldc[0]=512; m.N[0]=512; m.KS[0]=2; m.ntiles[0]=8; m.pstride[0]=524288;
        m.B[1]=w_k_idx; m.Cw[1]=kIP; m.ldb[1]=64;  m.wldc[1]=64;  m.N[1]=64;  m.KS[1]=2; m.ntiles[1]=1; m.pstride[1]=65536;
        m.ustart[0]=0; m.ustart[1]=16; m.ustart[2]=18;
        m.ne = 2;
        gemmk<<<dim3(18, 64), dim3(128), 0, stream>>>(m);
    }

    // ---- 2. weight transpose+cast to bf16 [N][K]
    {
        TC8 tc{};
        tc.src[0]=w_dkv; tc.dst[0]=wdkvT; tc.N[0]=256;  tc.Kld[0]=1024; tc.Ntiles[0]=4;
        tc.src[1]=w_dq;  tc.dst[1]=wdqT;  tc.N[1]=512;  tc.Kld[1]=1024; tc.Ntiles[1]=8;
        tc.src[2]=w_kr;  tc.dst[2]=wkrT;  tc.N[2]=32;   tc.Kld[2]=1024; tc.Ntiles[2]=1;
        tc.src[3]=w_uq;  tc.dst[3]=wuqT;  tc.N[3]=512;  tc.Kld[3]=512;  tc.Ntiles[3]=8;
        tc.src[4]=w_qr;  tc.dst[4]=wqrT;  tc.N[4]=256;  tc.Kld[4]=512;  tc.Ntiles[4]=4;
        tc.src[5]=w_uv;  tc.dst[5]=wuvT;  tc.N[5]=512;  tc.Kld[5]=256;  tc.Ntiles[5]=8;
        tc.src[6]=w_out; tc.dst[6]=woutT; tc.N[6]=1024; tc.Kld[6]=512;  tc.Ntiles[6]=16;
        int bs[8] = {0, 64, 192, 208, 272, 304, 336, 464};
        for (int i = 0; i < 8; ++i) tc.bstart[i] = bs[i];
        tc.ne = 7;
        tcast<<<dim3(464), dim3(256), 0, stream>>>(tc);
    }

    // ---- 3. stage-1 value projections (bf16 MFMA): ckv, cq, xkr
    {
        MFG m{};
        for (int i = 0; i < 3; ++i) { m.A[i]=x; m.lda[i]=1024; m.K[i]=1024; }
        m.B[0]=wdkvT; m.C[0]=ckv; m.ldb[0]=1024; m.ldc[0]=256; m.N[0]=256;
        m.B[1]=wdqT;  m.C[1]=cq;  m.ldb[1]=1024; m.ldc[1]=512; m.N[1]=512;
        m.B[2]=wkrT;  m.C[2]=xkr; m.ldb[2]=1024; m.ldc[2]=32;  m.N[2]=32;
        m.tstart[0]=0; m.tstart[1]=4; m.tstart[2]=12; m.tstart[3]=13;
        m.ne = 3;
        mgemm<<<dim3(13, 16), dim3(256), 0, stream>>>(m);
    }

    // ---- 4. small prep (mu/cos/sin need xkr; w_uk cast)
    prep_small<<<dim3(648), dim3(256), 0, stream>>>(xkr, raw_delta, w_uk, mu, cscb, cssb, wukb);

    // ---- 5. stage-2: qc, qrp (bf16 MFMA)
    {
        MFG m{};
        for (int i = 0; i < 2; ++i) { m.A[i]=cq; m.lda[i]=512; m.K[i]=512; }
        m.B[0]=wuqT; m.C[0]=qc;  m.ldb[0]=512; m.ldc[0]=512; m.N[0]=512;
        m.B[1]=wqrT; m.C[1]=qrp; m.ldb[1]=512; m.ldc[1]=256; m.N[1]=256;
        m.tstart[0]=0; m.tstart[1]=8; m.tstart[2]=12;
        m.ne = 2;
        mgemm<<<dim3(12, 16), dim3(256), 0, stream>>>(m);
    }

    pope_q_kernel<<<dim3(1024), dim3(128), 0, stream>>>(qrp, raw_delta, qrr);

    // ---- 6. qabs (bf16 MFMA, 8 head entries)
    {
        MFG m{};
        for (int h = 0; h < 8; ++h) {
            m.A[h] = qc + h * 64;   m.lda[h] = 512;  m.K[h] = 64;
            m.B[h] = wukb + h * 64; m.ldb[h] = 512;
            m.C[h] = qabs + h * 256; m.ldc[h] = 2048; m.N[h] = 256;
            m.tstart[h] = h * 4;
        }
        m.tstart[8] = 32;
        m.ne = 8;
        mgemm<<<dim3(32, 16), dim3(256), 0, stream>>>(m);
    }

    // ---- 7. indexer (fused split-K reduce) + exact top-k
    indexer_kernel<<<dim3(16, 32), dim3(256), 0, stream>>>(part, part + 1048576, w_idx, Ibuf);
    topk_kernel<<<dim3(256), dim3(256), 0, stream>>>(Ibuf, idxb);

    // ---- 8. fused attention -> olat (T14 async-stage)
    attn_kernel<<<dim3(1024), dim3(512), 0, stream>>>(qabs, qrr, ckv, mu, cscb, cssb, idxb, olat);

    // ---- 9. stage-3: outh_h = olat_h @ w_uv_h (bf16 MFMA)
    {
        MFG m{};
        for (int h = 0; h < 8; ++h) {
            m.A[h] = olat + h * 256;      m.lda[h] = 2048; m.K[h] = 256;
            m.B[h] = wuvT + h * 64 * 256; m.ldb[h] = 256;
            m.C[h] = outh + h * 64;       m.ldc[h] = 512;  m.N[h] = 64;
            m.tstart[h] = h;
        }
        m.tstart[8] = 8;
        m.ne = 8;
        mgemm<<<dim3(8, 16), dim3(256), 0, stream>>>(m);
    }

    // ---- 10. stage-4: out = outh @ w_out (bf16 MFMA)
    {
        MFG m{};
        m.A[0] = outh;  m.lda[0] = 512; m.K[0] = 512;
        m.B[0] = woutT; m.ldb[0] = 512;
        m.C[0] = out;   m.ldc[0] = 1024; m.N[0] = 1024;
        m.tstart[0] = 0; m.tstart[1] = 16;
        m.ne = 1;
        mgemm<<<dim3(16, 16), dim3(256), 0, stream>>>(m);
    }
}